// Round 1
// baseline (744.359 us; speedup 1.0000x reference)
//
#include <hip/hip_runtime.h>
#include <hip/hip_bf16.h>

typedef __attribute__((ext_vector_type(4))) float f32x4;
typedef __attribute__((ext_vector_type(8))) short s16x8;
typedef __attribute__((ext_vector_type(4))) short s16x4;

__device__ __forceinline__ short f2bf(float f) {
  union { float f; unsigned u; } c; c.f = f;
  unsigned r = c.u + 0x7fffu + ((c.u >> 16) & 1u);
  return (short)(r >> 16);
}
__device__ __forceinline__ float bf2f(short h) {
  union { unsigned u; float f; } c; c.u = ((unsigned)(unsigned short)h) << 16;
  return c.f;
}
__device__ __forceinline__ s16x8 cvt8(const f32x4& lo, const f32x4& hi) {
  s16x8 v;
  v[0] = f2bf(lo[0]); v[1] = f2bf(lo[1]); v[2] = f2bf(lo[2]); v[3] = f2bf(lo[3]);
  v[4] = f2bf(hi[0]); v[5] = f2bf(hi[1]); v[6] = f2bf(hi[2]); v[7] = f2bf(hi[3]);
  return v;
}

// ---------------------------------------------------------------------------
// Generic MFMA GEMM: C[M,N] = alpha * A[M,K] @ B[N,K]^T(+bias)(+res1)(+res2)
//   A: [M,K] row-major (fp32 or bf16), B: [N,K] row-major (fp32 or bf16)
//   C: fp32 or bf16. Batched via blockIdx.z with two-level (z/hb, z%hb) offsets.
//   BK=64. LDS chunk layout [k_grp][row ^ k_grp][8] -> conflict-free staging
//   writes and fragment reads.
// ---------------------------------------------------------------------------
template<int AF32, int BF32, int CF32, int BM, int BN, int RELU, int NRES>
__global__ __launch_bounds__(256, 2)
void gemm_k(const void* __restrict__ Ap, int hbA, long sAo, long sAi, int lda,
            const void* __restrict__ Bp, int hbB, long sBo, long sBi, int ldb,
            void* __restrict__ Cp, int hbC, long sCo, long sCi, int ldc,
            const float* __restrict__ bias,
            const float* __restrict__ res1,
            const float* __restrict__ res2,
            int M, int N, int K, float alpha)
{
  constexpr int MI = BM / 32, NI = BN / 32;     // frags per wave (2x2 wave grid)
  constexpr int ACH = BM / 32, BCH = BN / 32;   // staging chunks per thread
  __shared__ __align__(16) short smem[2][(BM + BN) * 64];

  const int tid  = threadIdx.x;
  const int lane = tid & 63;
  const int wid  = tid >> 6;
  const int wr   = wid >> 1, wc = wid & 1;
  const int z    = blockIdx.z;
  const int m0   = blockIdx.x * BM, n0 = blockIdx.y * BN;

  const int zA = z / hbA, zAi = z - zA * hbA;
  const int zB = z / hbB, zBi = z - zB * hbB;
  const int zC = z / hbC, zCi = z - zC * hbC;
  const char* Ab = (const char*)Ap + ((long)zA * sAo + (long)zAi * sAi) * (AF32 ? 4 : 2);
  const char* Bb = (const char*)Bp + ((long)zB * sBo + (long)zBi * sBi) * (BF32 ? 4 : 2);
  char*       Cb = (char*)Cp       + ((long)zC * sCo + (long)zCi * sCi) * (CF32 ? 4 : 2);

  const int kg = tid & 7;     // k-group 0..7
  const int rr = tid >> 3;    // 0..31

  long aoff[ACH]; int awr_[ACH];
  long boff[BCH]; int bwr_[BCH];
#pragma unroll
  for (int i = 0; i < ACH; ++i) {
    int r = rr + 32 * i;
    int gr = m0 + r; if (gr > M - 1) gr = M - 1;
    aoff[i] = (long)gr * lda + kg * 8;
    awr_[i] = (kg * BM + (r ^ kg)) * 8;
  }
#pragma unroll
  for (int i = 0; i < BCH; ++i) {
    int r = rr + 32 * i;
    int gc = n0 + r; if (gc > N - 1) gc = N - 1;
    boff[i] = (long)gc * ldb + kg * 8;
    bwr_[i] = BM * 64 + (kg * BN + (r ^ kg)) * 8;
  }

  f32x4 aF[ACH][2]; s16x8 aH[ACH];
  f32x4 bF[BCH][2]; s16x8 bH[BCH];

  auto loadT = [&](int kt) {
#pragma unroll
    for (int i = 0; i < ACH; ++i) {
      if constexpr (AF32) {
        const float* p = (const float*)Ab + aoff[i] + (long)kt * 64;
        aF[i][0] = *(const f32x4*)p; aF[i][1] = *(const f32x4*)(p + 4);
      } else {
        aH[i] = *(const s16x8*)((const short*)Ab + aoff[i] + (long)kt * 64);
      }
    }
#pragma unroll
    for (int i = 0; i < BCH; ++i) {
      if constexpr (BF32) {
        const float* p = (const float*)Bb + boff[i] + (long)kt * 64;
        bF[i][0] = *(const f32x4*)p; bF[i][1] = *(const f32x4*)(p + 4);
      } else {
        bH[i] = *(const s16x8*)((const short*)Bb + boff[i] + (long)kt * 64);
      }
    }
  };
  auto writeT = [&](int buf) {
#pragma unroll
    for (int i = 0; i < ACH; ++i) {
      s16x8 v;
      if constexpr (AF32) v = cvt8(aF[i][0], aF[i][1]); else v = aH[i];
      *(s16x8*)&smem[buf][awr_[i]] = v;
    }
#pragma unroll
    for (int i = 0; i < BCH; ++i) {
      s16x8 v;
      if constexpr (BF32) v = cvt8(bF[i][0], bF[i][1]); else v = bH[i];
      *(s16x8*)&smem[buf][bwr_[i]] = v;
    }
  };

  // fragment ds_read offsets (shorts)
  int ard[2][MI], brd[2][NI];
#pragma unroll
  for (int kk = 0; kk < 2; ++kk) {
    int kgr = kk * 4 + (lane >> 4);
#pragma unroll
    for (int mi = 0; mi < MI; ++mi) {
      int m = wr * (BM / 2) + mi * 16 + (lane & 15);
      ard[kk][mi] = (kgr * BM + (m ^ kgr)) * 8;
    }
#pragma unroll
    for (int ni = 0; ni < NI; ++ni) {
      int n = wc * (BN / 2) + ni * 16 + (lane & 15);
      brd[kk][ni] = BM * 64 + (kgr * BN + (n ^ kgr)) * 8;
    }
  }

  loadT(0);
  writeT(0);
  __syncthreads();

  f32x4 acc[MI][NI];
#pragma unroll
  for (int mi = 0; mi < MI; ++mi)
#pragma unroll
    for (int ni = 0; ni < NI; ++ni) acc[mi][ni] = (f32x4){0.f, 0.f, 0.f, 0.f};

  const int NT = K >> 6;
  for (int kt = 0; kt < NT; ++kt) {
    const int cur = kt & 1;
    if (kt + 1 < NT) loadT(kt + 1);

    s16x8 afr[2][MI], bfr[2][NI];
#pragma unroll
    for (int kk = 0; kk < 2; ++kk) {
#pragma unroll
      for (int mi = 0; mi < MI; ++mi) afr[kk][mi] = *(const s16x8*)&smem[cur][ard[kk][mi]];
#pragma unroll
      for (int ni = 0; ni < NI; ++ni) bfr[kk][ni] = *(const s16x8*)&smem[cur][brd[kk][ni]];
    }
#pragma unroll
    for (int kk = 0; kk < 2; ++kk)
#pragma unroll
      for (int mi = 0; mi < MI; ++mi)
#pragma unroll
        for (int ni = 0; ni < NI; ++ni)
          acc[mi][ni] = __builtin_amdgcn_mfma_f32_16x16x32_bf16(afr[kk][mi], bfr[kk][ni], acc[mi][ni], 0, 0, 0);

    if (kt + 1 < NT) {
      writeT(cur ^ 1);
      __syncthreads();
    }
  }

  // epilogue
#pragma unroll
  for (int mi = 0; mi < MI; ++mi) {
#pragma unroll
    for (int ni = 0; ni < NI; ++ni) {
      int col = n0 + wc * (BN / 2) + ni * 16 + (lane & 15);
      if (col < N) {
        float bv = bias ? bias[col] : 0.f;
        int rbase = m0 + wr * (BM / 2) + mi * 16 + ((lane >> 4) << 2);
#pragma unroll
        for (int j = 0; j < 4; ++j) {
          int r = rbase + j;
          if (r < M) {
            float v = acc[mi][ni][j] * alpha + bv;
            if constexpr (NRES >= 1) v += res1[(long)r * ldc + col];
            if constexpr (NRES >= 2) v += res2[(long)r * ldc + col];
            if constexpr (RELU) v = fmaxf(v, 0.f);
            if constexpr (CF32) ((float*)Cb)[(long)r * ldc + col] = v;
            else                ((short*)Cb)[(long)r * ldc + col] = f2bf(v);
          }
        }
      }
    }
  }
}

// ---------------------------------------------------------------------------
// Batched transpose: in [R_in x C] (fp32 or bf16, row stride rs_in) ->
// out bf16 [C x Rpad], zero-padding rows R_in..Rpad-1.
// ---------------------------------------------------------------------------
template<int INF32>
__global__ __launch_bounds__(256)
void transpose_k(const void* __restrict__ inp, short* __restrict__ outp,
                 int R_in, int rs_in, int Rpad, int tiles_r,
                 int hb, long sO, long sI, long out_bs)
{
  __shared__ float tile[64][65];
  const int z = blockIdx.y;
  const int zo = z / hb, zi = z - zo * hb;
  const char* in = (const char*)inp + ((long)zo * sO + (long)zi * sI) * (INF32 ? 4 : 2);
  short* out = outp + (long)z * out_bs;
  const int zt = blockIdx.x;
  const int tr = zt % tiles_r, tc = zt / tiles_r;
  const int r0 = tr * 64, c0 = tc * 64;
  const int c = threadIdx.x & 63, l0 = threadIdx.x >> 6;

#pragma unroll 4
  for (int i = 0; i < 16; ++i) {
    int l = l0 + i * 4;
    int gr = r0 + l;
    float v = 0.f;
    if (gr < R_in) {
      long off = (long)gr * rs_in + c0 + c;
      v = INF32 ? ((const float*)in)[off] : bf2f(((const short*)in)[off]);
    }
    tile[l][c] = v;
  }
  __syncthreads();
#pragma unroll 4
  for (int i = 0; i < 16; ++i) {
    int cr = l0 + i * 4;
    out[(long)(c0 + cr) * Rpad + r0 + c] = f2bf(tile[c][cr]);
  }
}

// ---------------------------------------------------------------------------
// LayerNorm over D=512, one wave per row
// ---------------------------------------------------------------------------
__global__ __launch_bounds__(256)
void ln_k(const float* __restrict__ in, const float* __restrict__ g,
          const float* __restrict__ b, float* __restrict__ out, int rows)
{
  int row = blockIdx.x * 4 + (threadIdx.x >> 6);
  if (row >= rows) return;
  int lane = threadIdx.x & 63;
  const float* p = in + (long)row * 512 + lane * 8;
  f32x4 v0 = *(const f32x4*)p, v1 = *(const f32x4*)(p + 4);
  float s = 0.f, sq = 0.f;
#pragma unroll
  for (int j = 0; j < 4; ++j) { s += v0[j] + v1[j]; sq += v0[j]*v0[j] + v1[j]*v1[j]; }
#pragma unroll
  for (int o = 1; o < 64; o <<= 1) { s += __shfl_xor(s, o); sq += __shfl_xor(sq, o); }
  float mean = s * (1.f / 512.f);
  float var  = sq * (1.f / 512.f) - mean * mean;
  float rs   = rsqrtf(var + 1e-6f);
  const f32x4 g0 = *(const f32x4*)(g + lane * 8), g1 = *(const f32x4*)(g + lane * 8 + 4);
  const f32x4 b0 = *(const f32x4*)(b + lane * 8), b1 = *(const f32x4*)(b + lane * 8 + 4);
  f32x4 o0, o1;
#pragma unroll
  for (int j = 0; j < 4; ++j) {
    o0[j] = g0[j] * (v0[j] - mean) * rs + b0[j];
    o1[j] = g1[j] * (v1[j] - mean) * rs + b1[j];
  }
  float* op = out + (long)row * 512 + lane * 8;
  *(f32x4*)op = o0; *(f32x4*)(op + 4) = o1;
}

// ---------------------------------------------------------------------------
// Row softmax over 256 bf16 columns (valid nvalid, rest masked->0), in place.
// ---------------------------------------------------------------------------
__global__ __launch_bounds__(256)
void softmax_k(short* __restrict__ S, int rows, int nvalid)
{
  int row = blockIdx.x * 4 + (threadIdx.x >> 6);
  if (row >= rows) return;
  int lane = threadIdx.x & 63;
  short* p = S + (long)row * 256 + lane * 4;
  s16x4 raw = *(const s16x4*)p;
  float x[4];
#pragma unroll
  for (int j = 0; j < 4; ++j) {
    int col = lane * 4 + j;
    x[j] = (col < nvalid) ? bf2f(raw[j]) : -3.0e38f;
  }
  float m = fmaxf(fmaxf(x[0], x[1]), fmaxf(x[2], x[3]));
#pragma unroll
  for (int o = 1; o < 64; o <<= 1) m = fmaxf(m, __shfl_xor(m, o));
  float e[4]; float s = 0.f;
#pragma unroll
  for (int j = 0; j < 4; ++j) {
    int col = lane * 4 + j;
    e[j] = (col < nvalid) ? __expf(x[j] - m) : 0.f;
    s += e[j];
  }
#pragma unroll
  for (int o = 1; o < 64; o <<= 1) s += __shfl_xor(s, o);
  float inv = 1.f / s;
  s16x4 ov;
#pragma unroll
  for (int j = 0; j < 4; ++j) ov[j] = f2bf(e[j] * inv);
  *(s16x4*)p = ov;
}

// ---------------------------------------------------------------------------
static inline int ceildiv(int a, int b) { return (a + b - 1) / b; }

template<int AF32, int BF32, int CF32, int BM, int BN, int RELU, int NRES>
static void launch_gemm(hipStream_t st, int gm, int gn, int gz,
                        const void* A, int hbA, long sAo, long sAi, int lda,
                        const void* B, int hbB, long sBo, long sBi, int ldb,
                        void* C, int hbC, long sCo, long sCi, int ldc,
                        const float* bias, const float* r1, const float* r2,
                        int M, int N, int K, float alpha)
{
  gemm_k<AF32, BF32, CF32, BM, BN, RELU, NRES>
      <<<dim3(gm, gn, gz), dim3(256), 0, st>>>(
          A, hbA, sAo, sAi, lda, B, hbB, sBo, sBi, ldb,
          C, hbC, sCo, sCi, ldc, bias, r1, r2, M, N, K, alpha);
}

extern "C" void kernel_launch(void* const* d_in, const int* in_sizes, int n_in,
                              void* d_out, int out_size, void* d_ws, size_t ws_size,
                              hipStream_t stream)
{
  (void)in_sizes; (void)n_in; (void)out_size; (void)ws_size;

  const float* x     = (const float*)d_in[0];   // [32,256,512]
  const float* text  = (const float*)d_in[1];   // [32,256,512]
  const float* vis   = (const float*)d_in[2];   // [32,196,512]
  const float* ftw   = (const float*)d_in[3];   // [4,512,512]
  const float* ftb   = (const float*)d_in[4];   // [4,512]
  const float* ftw1  = (const float*)d_in[5];   // [512,2048]
  const float* ftb1  = (const float*)d_in[6];
  const float* ftw2  = (const float*)d_in[7];   // [2048,512]
  const float* ftb2  = (const float*)d_in[8];
  const float* ftln  = (const float*)d_in[9];   // [2,2,512]
  const float* fvw   = (const float*)d_in[10];
  const float* fvb   = (const float*)d_in[11];
  const float* fvw1  = (const float*)d_in[12];
  const float* fvb1  = (const float*)d_in[13];
  const float* fvw2  = (const float*)d_in[14];
  const float* fvb2  = (const float*)d_in[15];
  const float* fvln  = (const float*)d_in[16];
  const float* ldmln = (const float*)d_in[17];  // [2,512]
  const float* afw   = (const float*)d_in[18];  // [2,2,512,512]
  const float* afb   = (const float*)d_in[19];  // [2,2,512]
  float* out = (float*)d_out;

  char* ws = (char*)d_ws;
  short* wT    = (short*)ws;                       // 7,340,032 bf16
  short* bufQ  = (short*)(ws + 14680064);          // 8,388,608 B
  short* bufK  = (short*)(ws + 23068672);
  short* bufV  = (short*)(ws + 31457280);
  short* bufT  = (short*)(ws + 39845888);
  short* bufS  = (short*)(ws + 48234496);          // 25,690,112 B (also FFN hidden)
  float* bufO  = (float*)(ws + 73924608);          // 16,777,216 B
  float* bufX1 = (float*)(ws + 90701824);          // 12,845,056 B
  float* bufA2 = (float*)(ws + 103546880);
  float* bufMED= (float*)(ws + 116391936);
  float* bufVAF= (float*)(ws + 129236992);
  float* bufLN = out;                              // scratch reuse of d_out

  short* ftWq  = wT + 0;
  short* ftWk  = wT + 262144;
  short* ftWv  = wT + 524288;
  short* ftWo  = wT + 786432;
  short* ftW1t = wT + 1048576;
  short* ftW2t = wT + 2097152;
  short* fvWq  = wT + 3145728;
  short* fvWk  = wT + 3407872;
  short* fvWv  = wT + 3670016;
  short* fvWo  = wT + 3932160;
  short* fvW1t = wT + 4194304;
  short* fvW2t = wT + 5242880;
  short* afW00 = wT + 6291456;
  short* afW01 = wT + 6553600;
  short* afW10 = wT + 6815744;
  short* afW11 = wT + 7077888;

  const float AFS = 0.04419417382415922f; // 1/sqrt(512)
  dim3 blk(256);

  // ---- weight prep: transpose+convert to bf16 [N][K] ----
  transpose_k<1><<<dim3(64, 4), blk, 0, stream>>>(ftw,  ftWq,  512, 512, 512, 8, 1, 262144L, 0L, 262144L);
  transpose_k<1><<<dim3(256,1), blk, 0, stream>>>(ftw1, ftW1t, 512, 2048, 512, 8, 1, 0L, 0L, 0L);
  transpose_k<1><<<dim3(256,1), blk, 0, stream>>>(ftw2, ftW2t, 2048, 512, 2048, 32, 1, 0L, 0L, 0L);
  transpose_k<1><<<dim3(64, 4), blk, 0, stream>>>(fvw,  fvWq,  512, 512, 512, 8, 1, 262144L, 0L, 262144L);
  transpose_k<1><<<dim3(256,1), blk, 0, stream>>>(fvw1, fvW1t, 512, 2048, 512, 8, 1, 0L, 0L, 0L);
  transpose_k<1><<<dim3(256,1), blk, 0, stream>>>(fvw2, fvW2t, 2048, 512, 2048, 32, 1, 0L, 0L, 0L);
  transpose_k<1><<<dim3(64, 4), blk, 0, stream>>>(afw,  afW00, 512, 512, 512, 8, 1, 262144L, 0L, 262144L);

  // ================= Phase A: cross_layer(vis, text, ft) =================
  ln_k<<<ceildiv(6272,4), blk, 0, stream>>>(vis, ftln + 0, ftln + 512, bufLN, 6272);
  launch_gemm<1,0,0,128,64,0,0>(stream, 49,8,1, bufLN,1,0,0,512, ftWq,1,0,0,512,
      bufQ,1,0,0,512, ftb + 0, nullptr, nullptr, 6272,512,512, 1.f);
  launch_gemm<1,0,0,128,64,0,0>(stream, 64,8,1, text,1,0,0,512, ftWk,1,0,0,512,
      bufK,1,0,0,512, ftb + 512, nullptr, nullptr, 8192,512,512, 1.f);
  launch_gemm<1,0,0,128,64,0,0>(stream, 64,8,1, text,1,0,0,512, ftWv,1,0,0,512,
      bufV,1,0,0,512, ftb + 1024, nullptr, nullptr, 8192,512,512, 1.f);
  transpose_k<0><<<dim3(4,256), blk, 0, stream>>>(bufV, bufT, 256, 512, 256, 4, 8, 131072L, 64L, 16384L);
  launch_gemm<0,0,0,64,64,0,0>(stream, 4,4,256, bufQ,8,100352L,64L,512, bufK,8,131072L,64L,512,
      bufS,1,50176L,0L,256, nullptr, nullptr, nullptr, 196,256,64, 0.125f);
  softmax_k<<<ceildiv(50176,4), blk, 0, stream>>>(bufS, 50176, 256);
  launch_gemm<0,0,1,64,64,0,0>(stream, 4,1,256, bufS,1,50176L,0L,256, bufT,1,16384L,0L,256,
      bufO,8,100352L,64L,512, nullptr, nullptr, nullptr, 196,64,256, 1.f);
  launch_gemm<1,0,1,128,64,0,1>(stream, 49,8,1, bufO,1,0,0,512, ftWo,1,0,0,512,
      bufX1,1,0,0,512, ftb + 1536, vis, nullptr, 6272,512,512, 1.f);
  ln_k<<<ceildiv(6272,4), blk, 0, stream>>>(bufX1, ftln + 1024, ftln + 1536, bufLN, 6272);
  launch_gemm<1,0,0,128,128,1,0>(stream, 49,16,1, bufLN,1,0,0,512, ftW1t,1,0,0,512,
      bufS,1,0,0,2048, ftb1, nullptr, nullptr, 6272,2048,512, 1.f);
  launch_gemm<0,0,1,128,64,0,1>(stream, 49,8,1, bufS,1,0,0,2048, ftW2t,1,0,0,2048,
      bufX1,1,0,0,512, ftb2, bufX1, nullptr, 6272,512,2048, 1.f);

  // ================= Phase B: cross_layer(med1, vis, fv) + med1 =================
  ln_k<<<ceildiv(6272,4), blk, 0, stream>>>(bufX1, fvln + 0, fvln + 512, bufLN, 6272);
  launch_gemm<1,0,0,128,64,0,0>(stream, 49,8,1, bufLN,1,0,0,512, fvWq,1,0,0,512,
      bufQ,1,0,0,512, fvb + 0, nullptr, nullptr, 6272,512,512, 1.f);
  launch_gemm<1,0,0,128,64,0,0>(stream, 49,8,1, vis,1,0,0,512, fvWk,1,0,0,512,
      bufK,1,0,0,512, fvb + 512, nullptr, nullptr, 6272,512,512, 1.f);
  launch_gemm<1,0,0,128,64,0,0>(stream, 49,8,1, vis,1,0,0,512, fvWv,1,0,0,512,
      bufV,1,0,0,512, fvb + 1024, nullptr, nullptr, 6272,512,512, 1.f);
  transpose_k<0><<<dim3(4,256), blk, 0, stream>>>(bufV, bufT, 196, 512, 256, 4, 8, 100352L, 64L, 16384L);
  launch_gemm<0,0,0,64,64,0,0>(stream, 4,4,256, bufQ,8,100352L,64L,512, bufK,8,100352L,64L,512,
      bufS,1,50176L,0L,256, nullptr, nullptr, nullptr, 196,196,64, 0.125f);
  softmax_k<<<ceildiv(50176,4), blk, 0, stream>>>(bufS, 50176, 196);
  launch_gemm<0,0,1,64,64,0,0>(stream, 4,1,256, bufS,1,50176L,0L,256, bufT,1,16384L,0L,256,
      bufO,8,100352L,64L,512, nullptr, nullptr, nullptr, 196,64,256, 1.f);
  launch_gemm<1,0,1,128,64,0,1>(stream, 49,8,1, bufO,1,0,0,512, fvWo,1,0,0,512,
      bufA2,1,0,0,512, fvb + 1536, bufX1, nullptr, 6272,512,512, 1.f);
  ln_k<<<ceildiv(6272,4), blk, 0, stream>>>(bufA2, fvln + 1024, fvln + 1536, bufLN, 6272);
  launch_gemm<1,0,0,128,128,1,0>(stream, 49,16,1, bufLN,1,0,0,512, fvW1t,1,0,0,512,
      bufS,1,0,0,2048, fvb1, nullptr, nullptr, 6272,2048,512, 1.f);
  launch_gemm<0,0,1,128,64,0,2>(stream, 49,8,1, bufS,1,0,0,2048, fvW2t,1,0,0,2048,
      bufA2,1,0,0,512, fvb2, bufA2, bufX1, 6272,512,2048, 1.f);
  ln_k<<<ceildiv(6272,4), blk, 0, stream>>>(bufA2, ldmln + 0, ldmln + 512, bufMED, 6272);

  // ================= Phase C: v_af = af(med, x, x) =================
  transpose_k<1><<<dim3(32,32), blk, 0, stream>>>(x, bufT, 256, 512, 256, 4, 1, 131072L, 0L, 131072L);
  launch_gemm<1,0,0,128,64,0,0>(stream, 49,8,1, bufMED,1,0,0,512, afW00,1,0,0,512,
      bufQ,1,0,0,512, afb + 0, nullptr, nullptr, 6272,512,512, 1.f);
  launch_gemm<0,1,0,64,64,0,0>(stream, 4,4,32, bufQ,1,100352L,0L,512, x,1,131072L,0L,512,
      bufS,1,50176L,0L,256, nullptr, nullptr, nullptr, 196,256,512, AFS);
  softmax_k<<<ceildiv(6272,4), blk, 0, stream>>>(bufS, 6272, 256);
  launch_gemm<0,0,1,64,64,0,0>(stream, 4,8,32, bufS,1,50176L,0L,256, bufT,1,131072L,0L,256,
      bufO,1,100352L,0L,512, nullptr, nullptr, nullptr, 196,512,256, 1.f);
  launch_gemm<1,0,1,128,64,0,0>(stream, 49,8,1, bufO,1,0,0,512, afW01,1,0,0,512,
      bufVAF,1,0,0,512, afb + 512, nullptr, nullptr, 6272,512,512, 1.f);
  transpose_k<1><<<dim3(32,32), blk, 0, stream>>>(bufVAF, bufT, 196, 512, 256, 4, 1, 100352L, 0L, 131072L);

  // ================= Phase D: out = af(x, med, v_af) + x =================
  launch_gemm<1,0,0,128,64,0,0>(stream, 64,8,1, x,1,0,0,512, afW10,1,0,0,512,
      bufQ,1,0,0,512, afb + 1024, nullptr, nullptr, 8192,512,512, 1.f);
  launch_gemm<0,1,0,64,64,0,0>(stream, 4,4,32, bufQ,1,131072L,0L,512, bufMED,1,100352L,0L,512,
      bufS,1,65536L,0L,256, nullptr, nullptr, nullptr, 256,196,512, AFS);
  softmax_k<<<ceildiv(8192,4), blk, 0, stream>>>(bufS, 8192, 196);
  launch_gemm<0,0,1,64,64,0,0>(stream, 4,8,32, bufS,1,65536L,0L,256, bufT,1,131072L,0L,256,
      bufO,1,131072L,0L,512, nullptr, nullptr, nullptr, 256,512,256, 1.f);
  launch_gemm<1,0,1,128,64,0,1>(stream, 64,8,1, bufO,1,0,0,512, afW11,1,0,0,512,
      out,1,0,0,512, afb + 1536, x, nullptr, 8192,512,512, 1.f);
}

// Round 2
// 607.670 us; speedup vs baseline: 1.2249x; 1.2249x over previous
//
#include <hip/hip_runtime.h>
#include <hip/hip_bf16.h>

typedef __attribute__((ext_vector_type(4))) float f32x4;
typedef __attribute__((ext_vector_type(8))) short s16x8;
typedef __attribute__((ext_vector_type(4))) short s16x4;

__device__ __forceinline__ short f2bf(float f) {
  union { float f; unsigned u; } c; c.f = f;
  unsigned r = c.u + 0x7fffu + ((c.u >> 16) & 1u);
  return (short)(r >> 16);
}
__device__ __forceinline__ float bf2f(short h) {
  union { unsigned u; float f; } c; c.u = ((unsigned)(unsigned short)h) << 16;
  return c.f;
}
__device__ __forceinline__ s16x8 cvt8(const f32x4& lo, const f32x4& hi) {
  s16x8 v;
  v[0] = f2bf(lo[0]); v[1] = f2bf(lo[1]); v[2] = f2bf(lo[2]); v[3] = f2bf(lo[3]);
  v[4] = f2bf(hi[0]); v[5] = f2bf(hi[1]); v[6] = f2bf(hi[2]); v[7] = f2bf(hi[3]);
  return v;
}

// ---------------------------------------------------------------------------
// Generic MFMA GEMM: C[M,N] = alpha * A[M,K] @ B[N,K]^T(+bias)(+res1)(+res2)
//   SWZ=1: XCD-chunked bijective remap (each XCD gets contiguous m-chunk x all n)
// ---------------------------------------------------------------------------
template<int AF32, int BF32, int CF32, int BM, int BN, int RELU, int NRES, int SWZ>
__global__ __launch_bounds__(256, 2)
void gemm_k(const void* __restrict__ Ap, int hbA, long sAo, long sAi, int lda,
            const void* __restrict__ Bp, int hbB, long sBo, long sBi, int ldb,
            void* __restrict__ Cp, int hbC, long sCo, long sCi, int ldc,
            const float* __restrict__ bias,
            const float* __restrict__ res1,
            const float* __restrict__ res2,
            int M, int N, int K, float alpha)
{
  constexpr int MI = BM / 32, NI = BN / 32;
  constexpr int ACH = BM / 32, BCH = BN / 32;
  __shared__ __align__(16) short smem[2][(BM + BN) * 64];

  const int tid  = threadIdx.x;
  const int lane = tid & 63;
  const int wid  = tid >> 6;
  const int wr   = wid >> 1, wc = wid & 1;
  const int z    = blockIdx.z;

  int bx = blockIdx.x, by = blockIdx.y;
  if constexpr (SWZ) {
    const int gx = gridDim.x, gy = gridDim.y;
    const int nwg = gx * gy;
    const int o = by * gx + bx;             // HW dispatch order (x fastest)
    const int q = nwg >> 3, r = nwg & 7;
    const int xcd = o & 7, slot = o >> 3;
    const int w = (xcd < r ? xcd * (q + 1) : r * (q + 1) + (xcd - r) * q) + slot;
    bx = w / gy; by = w - bx * gy;          // n fastest within chunk
  }
  const int m0 = bx * BM, n0 = by * BN;

  const int zA = z / hbA, zAi = z - zA * hbA;
  const int zB = z / hbB, zBi = z - zB * hbB;
  const int zC = z / hbC, zCi = z - zC * hbC;
  const char* Ab = (const char*)Ap + ((long)zA * sAo + (long)zAi * sAi) * (AF32 ? 4 : 2);
  const char* Bb = (const char*)Bp + ((long)zB * sBo + (long)zBi * sBi) * (BF32 ? 4 : 2);
  char*       Cb = (char*)Cp       + ((long)zC * sCo + (long)zCi * sCi) * (CF32 ? 4 : 2);

  const int kg = tid & 7;     // k-group 0..7
  const int rr = tid >> 3;    // 0..31

  long aoff[ACH]; int awr_[ACH];
  long boff[BCH]; int bwr_[BCH];
#pragma unroll
  for (int i = 0; i < ACH; ++i) {
    int r = rr + 32 * i;
    int gr = m0 + r; if (gr > M - 1) gr = M - 1;
    aoff[i] = (long)gr * lda + kg * 8;
    awr_[i] = (kg * BM + (r ^ kg)) * 8;
  }
#pragma unroll
  for (int i = 0; i < BCH; ++i) {
    int r = rr + 32 * i;
    int gc = n0 + r; if (gc > N - 1) gc = N - 1;
    boff[i] = (long)gc * ldb + kg * 8;
    bwr_[i] = BM * 64 + (kg * BN + (r ^ kg)) * 8;
  }

  f32x4 aF[ACH][2]; s16x8 aH[ACH];
  f32x4 bF[BCH][2]; s16x8 bH[BCH];

  auto loadT = [&](int kt) {
#pragma unroll
    for (int i = 0; i < ACH; ++i) {
      if constexpr (AF32) {
        const float* p = (const float*)Ab + aoff[i] + (long)kt * 64;
        aF[i][0] = *(const f32x4*)p; aF[i][1] = *(const f32x4*)(p + 4);
      } else {
        aH[i] = *(const s16x8*)((const short*)Ab + aoff[i] + (long)kt * 64);
      }
    }
#pragma unroll
    for (int i = 0; i < BCH; ++i) {
      if constexpr (BF32) {
        const float* p = (const float*)Bb + boff[i] + (long)kt * 64;
        bF[i][0] = *(const f32x4*)p; bF[i][1] = *(const f32x4*)(p + 4);
      } else {
        bH[i] = *(const s16x8*)((const short*)Bb + boff[i] + (long)kt * 64);
      }
    }
  };
  auto writeT = [&](int buf) {
#pragma unroll
    for (int i = 0; i < ACH; ++i) {
      s16x8 v;
      if constexpr (AF32) v = cvt8(aF[i][0], aF[i][1]); else v = aH[i];
      *(s16x8*)&smem[buf][awr_[i]] = v;
    }
#pragma unroll
    for (int i = 0; i < BCH; ++i) {
      s16x8 v;
      if constexpr (BF32) v = cvt8(bF[i][0], bF[i][1]); else v = bH[i];
      *(s16x8*)&smem[buf][bwr_[i]] = v;
    }
  };

  int ard[2][MI], brd[2][NI];
#pragma unroll
  for (int kk = 0; kk < 2; ++kk) {
    int kgr = kk * 4 + (lane >> 4);
#pragma unroll
    for (int mi = 0; mi < MI; ++mi) {
      int m = wr * (BM / 2) + mi * 16 + (lane & 15);
      ard[kk][mi] = (kgr * BM + (m ^ kgr)) * 8;
    }
#pragma unroll
    for (int ni = 0; ni < NI; ++ni) {
      int n = wc * (BN / 2) + ni * 16 + (lane & 15);
      brd[kk][ni] = BM * 64 + (kgr * BN + (n ^ kgr)) * 8;
    }
  }

  loadT(0);
  writeT(0);
  __syncthreads();

  f32x4 acc[MI][NI];
#pragma unroll
  for (int mi = 0; mi < MI; ++mi)
#pragma unroll
    for (int ni = 0; ni < NI; ++ni) acc[mi][ni] = (f32x4){0.f, 0.f, 0.f, 0.f};

  const int NT = K >> 6;
  for (int kt = 0; kt < NT; ++kt) {
    const int cur = kt & 1;
    if (kt + 1 < NT) loadT(kt + 1);

    s16x8 afr[2][MI], bfr[2][NI];
#pragma unroll
    for (int kk = 0; kk < 2; ++kk) {
#pragma unroll
      for (int mi = 0; mi < MI; ++mi) afr[kk][mi] = *(const s16x8*)&smem[cur][ard[kk][mi]];
#pragma unroll
      for (int ni = 0; ni < NI; ++ni) bfr[kk][ni] = *(const s16x8*)&smem[cur][brd[kk][ni]];
    }
#pragma unroll
    for (int kk = 0; kk < 2; ++kk)
#pragma unroll
      for (int mi = 0; mi < MI; ++mi)
#pragma unroll
        for (int ni = 0; ni < NI; ++ni)
          acc[mi][ni] = __builtin_amdgcn_mfma_f32_16x16x32_bf16(afr[kk][mi], bfr[kk][ni], acc[mi][ni], 0, 0, 0);

    if (kt + 1 < NT) {
      writeT(cur ^ 1);
      __syncthreads();
    }
  }

#pragma unroll
  for (int mi = 0; mi < MI; ++mi) {
#pragma unroll
    for (int ni = 0; ni < NI; ++ni) {
      int col = n0 + wc * (BN / 2) + ni * 16 + (lane & 15);
      if (col < N) {
        float bv = bias ? bias[col] : 0.f;
        int rbase = m0 + wr * (BM / 2) + mi * 16 + ((lane >> 4) << 2);
#pragma unroll
        for (int j = 0; j < 4; ++j) {
          int r = rbase + j;
          if (r < M) {
            float v = acc[mi][ni][j] * alpha + bv;
            if constexpr (NRES >= 1) v += res1[(long)r * ldc + col];
            if constexpr (NRES >= 2) v += res2[(long)r * ldc + col];
            if constexpr (RELU) v = fmaxf(v, 0.f);
            if constexpr (CF32) ((float*)Cb)[(long)r * ldc + col] = v;
            else                ((short*)Cb)[(long)r * ldc + col] = f2bf(v);
          }
        }
      }
    }
  }
}

// ---------------------------------------------------------------------------
// Batched transpose -> bf16 [C x Rpad], zero-pad rows R_in..Rpad-1
// ---------------------------------------------------------------------------
template<int INF32>
__global__ __launch_bounds__(256)
void transpose_k(const void* __restrict__ inp, short* __restrict__ outp,
                 int R_in, int rs_in, int Rpad, int tiles_r,
                 int hb, long sO, long sI, long out_bs)
{
  __shared__ float tile[64][65];
  const int z = blockIdx.y;
  const int zo = z / hb, zi = z - zo * hb;
  const char* in = (const char*)inp + ((long)zo * sO + (long)zi * sI) * (INF32 ? 4 : 2);
  short* out = outp + (long)z * out_bs;
  const int zt = blockIdx.x;
  const int tr = zt % tiles_r, tc = zt / tiles_r;
  const int r0 = tr * 64, c0 = tc * 64;
  const int c = threadIdx.x & 63, l0 = threadIdx.x >> 6;

#pragma unroll 4
  for (int i = 0; i < 16; ++i) {
    int l = l0 + i * 4;
    int gr = r0 + l;
    float v = 0.f;
    if (gr < R_in) {
      long off = (long)gr * rs_in + c0 + c;
      v = INF32 ? ((const float*)in)[off] : bf2f(((const short*)in)[off]);
    }
    tile[l][c] = v;
  }
  __syncthreads();
#pragma unroll 4
  for (int i = 0; i < 16; ++i) {
    int cr = l0 + i * 4;
    out[(long)(c0 + cr) * Rpad + r0 + c] = f2bf(tile[c][cr]);
  }
}

// ---------------------------------------------------------------------------
// fp32 -> bf16 bulk convert (n multiple of 2048)
// ---------------------------------------------------------------------------
__global__ __launch_bounds__(256)
void cvt_k(const float* __restrict__ in, short* __restrict__ out, long n)
{
  long i = ((long)blockIdx.x * 256 + threadIdx.x) * 8;
  if (i >= n) return;
  f32x4 a = *(const f32x4*)(in + i), b = *(const f32x4*)(in + i + 4);
  *(s16x8*)(out + i) = cvt8(a, b);
}

// ---------------------------------------------------------------------------
// LayerNorm over D=512, one wave per row; OF32 selects output dtype
// ---------------------------------------------------------------------------
template<int OF32>
__global__ __launch_bounds__(256)
void ln_k(const float* __restrict__ in, const float* __restrict__ g,
          const float* __restrict__ b, void* __restrict__ outp, int rows)
{
  int row = blockIdx.x * 4 + (threadIdx.x >> 6);
  if (row >= rows) return;
  int lane = threadIdx.x & 63;
  const float* p = in + (long)row * 512 + lane * 8;
  f32x4 v0 = *(const f32x4*)p, v1 = *(const f32x4*)(p + 4);
  float s = 0.f, sq = 0.f;
#pragma unroll
  for (int j = 0; j < 4; ++j) { s += v0[j] + v1[j]; sq += v0[j]*v0[j] + v1[j]*v1[j]; }
#pragma unroll
  for (int o = 1; o < 64; o <<= 1) { s += __shfl_xor(s, o); sq += __shfl_xor(sq, o); }
  float mean = s * (1.f / 512.f);
  float var  = sq * (1.f / 512.f) - mean * mean;
  float rs   = rsqrtf(var + 1e-6f);
  const f32x4 g0 = *(const f32x4*)(g + lane * 8), g1 = *(const f32x4*)(g + lane * 8 + 4);
  const f32x4 b0 = *(const f32x4*)(b + lane * 8), b1 = *(const f32x4*)(b + lane * 8 + 4);
  f32x4 o0, o1;
#pragma unroll
  for (int j = 0; j < 4; ++j) {
    o0[j] = g0[j] * (v0[j] - mean) * rs + b0[j];
    o1[j] = g1[j] * (v1[j] - mean) * rs + b1[j];
  }
  if constexpr (OF32) {
    float* op = (float*)outp + (long)row * 512 + lane * 8;
    *(f32x4*)op = o0; *(f32x4*)(op + 4) = o1;
  } else {
    short* op = (short*)outp + (long)row * 512 + lane * 8;
    *(s16x8*)op = cvt8(o0, o1);
  }
}

// ---------------------------------------------------------------------------
// Row softmax over 256 bf16 columns (valid nvalid, rest -> 0), in place.
// ---------------------------------------------------------------------------
__global__ __launch_bounds__(256)
void softmax_k(short* __restrict__ S, int rows, int nvalid)
{
  int row = blockIdx.x * 4 + (threadIdx.x >> 6);
  if (row >= rows) return;
  int lane = threadIdx.x & 63;
  short* p = S + (long)row * 256 + lane * 4;
  s16x4 raw = *(const s16x4*)p;
  float x[4];
#pragma unroll
  for (int j = 0; j < 4; ++j) {
    int col = lane * 4 + j;
    x[j] = (col < nvalid) ? bf2f(raw[j]) : -3.0e38f;
  }
  float m = fmaxf(fmaxf(x[0], x[1]), fmaxf(x[2], x[3]));
#pragma unroll
  for (int o = 1; o < 64; o <<= 1) m = fmaxf(m, __shfl_xor(m, o));
  float e[4]; float s = 0.f;
#pragma unroll
  for (int j = 0; j < 4; ++j) {
    int col = lane * 4 + j;
    e[j] = (col < nvalid) ? __expf(x[j] - m) : 0.f;
    s += e[j];
  }
#pragma unroll
  for (int o = 1; o < 64; o <<= 1) s += __shfl_xor(s, o);
  float inv = 1.f / s;
  s16x4 ov;
#pragma unroll
  for (int j = 0; j < 4; ++j) ov[j] = f2bf(e[j] * inv);
  *(s16x4*)p = ov;
}

// ---------------------------------------------------------------------------
static inline int ceildiv(int a, int b) { return (a + b - 1) / b; }

template<int AF32, int BF32, int CF32, int BM, int BN, int RELU, int NRES, int SWZ>
static void launch_gemm(hipStream_t st, int gm, int gn, int gz,
                        const void* A, int hbA, long sAo, long sAi, int lda,
                        const void* B, int hbB, long sBo, long sBi, int ldb,
                        void* C, int hbC, long sCo, long sCi, int ldc,
                        const float* bias, const float* r1, const float* r2,
                        int M, int N, int K, float alpha)
{
  gemm_k<AF32, BF32, CF32, BM, BN, RELU, NRES, SWZ>
      <<<dim3(gm, gn, gz), dim3(256), 0, st>>>(
          A, hbA, sAo, sAi, lda, B, hbB, sBo, sBi, ldb,
          C, hbC, sCo, sCi, ldc, bias, r1, r2, M, N, K, alpha);
}

extern "C" void kernel_launch(void* const* d_in, const int* in_sizes, int n_in,
                              void* d_out, int out_size, void* d_ws, size_t ws_size,
                              hipStream_t stream)
{
  (void)in_sizes; (void)n_in; (void)out_size; (void)ws_size;

  const float* x     = (const float*)d_in[0];   // [32,256,512]
  const float* text  = (const float*)d_in[1];   // [32,256,512]
  const float* vis   = (const float*)d_in[2];   // [32,196,512]
  const float* ftw   = (const float*)d_in[3];   // [4,512,512]
  const float* ftb   = (const float*)d_in[4];   // [4,512]
  const float* ftw1  = (const float*)d_in[5];   // [512,2048]
  const float* ftb1  = (const float*)d_in[6];
  const float* ftw2  = (const float*)d_in[7];   // [2048,512]
  const float* ftb2  = (const float*)d_in[8];
  const float* ftln  = (const float*)d_in[9];   // [2,2,512]
  const float* fvw   = (const float*)d_in[10];
  const float* fvb   = (const float*)d_in[11];
  const float* fvw1  = (const float*)d_in[12];
  const float* fvb1  = (const float*)d_in[13];
  const float* fvw2  = (const float*)d_in[14];
  const float* fvb2  = (const float*)d_in[15];
  const float* fvln  = (const float*)d_in[16];
  const float* ldmln = (const float*)d_in[17];  // [2,512]
  const float* afw   = (const float*)d_in[18];  // [2,2,512,512]
  const float* afb   = (const float*)d_in[19];  // [2,2,512]
  float* out = (float*)d_out;

  char* ws = (char*)d_ws;
  short* wT    = (short*)ws;                     // 14,680,064 B of bf16 weights
  short* xbf   = (short*)(ws + 14680064);        // 8,388,608 B  [32,256,512] bf16
  short* bufLN = (short*)(ws + 23068672);        // 6,422,528 B  [6272,512] bf16
  short* bufQ  = (short*)(ws + 29491200);        // 8,388,608 B
  short* bufK  = (short*)(ws + 37879808);        // 8,388,608 B (reused as v_af)
  short* bufV  = (short*)(ws + 46268416);        // 8,388,608 B
  short* bufT  = (short*)(ws + 54657024);        // 8,388,608 B
  short* bufS  = (short*)(ws + 63045632);        // 25,690,112 B (scores / FFN hidden)
  short* bufO  = (short*)(ws + 88735744);        // 8,388,608 B
  float* bufX1 = (float*)(ws + 97124352);        // 12,845,056 B fp32 residual
  float* bufA2 = (float*)(ws + 109969408);       // 12,845,056 B fp32 residual
  short* bufMED= (short*)(ws + 122814464);       // 6,422,528 B bf16 LN(med)

  short* ftWq  = wT + 0;
  short* ftWk  = wT + 262144;
  short* ftWv  = wT + 524288;
  short* ftWo  = wT + 786432;
  short* ftW1t = wT + 1048576;
  short* ftW2t = wT + 2097152;
  short* fvWq  = wT + 3145728;
  short* fvWk  = wT + 3407872;
  short* fvWv  = wT + 3670016;
  short* fvWo  = wT + 3932160;
  short* fvW1t = wT + 4194304;
  short* fvW2t = wT + 5242880;
  short* afW00 = wT + 6291456;
  short* afW01 = wT + 6553600;
  short* afW10 = wT + 6815744;
  short* afW11 = wT + 7077888;

  const float AFS = 0.04419417382415922f; // 1/sqrt(512)
  dim3 blk(256);

  // ---- prep: weight transpose+convert, x -> bf16 ----
  transpose_k<1><<<dim3(64, 4), blk, 0, stream>>>(ftw,  ftWq,  512, 512, 512, 8, 1, 262144L, 0L, 262144L);
  transpose_k<1><<<dim3(256,1), blk, 0, stream>>>(ftw1, ftW1t, 512, 2048, 512, 8, 1, 0L, 0L, 0L);
  transpose_k<1><<<dim3(256,1), blk, 0, stream>>>(ftw2, ftW2t, 2048, 512, 2048, 32, 1, 0L, 0L, 0L);
  transpose_k<1><<<dim3(64, 4), blk, 0, stream>>>(fvw,  fvWq,  512, 512, 512, 8, 1, 262144L, 0L, 262144L);
  transpose_k<1><<<dim3(256,1), blk, 0, stream>>>(fvw1, fvW1t, 512, 2048, 512, 8, 1, 0L, 0L, 0L);
  transpose_k<1><<<dim3(256,1), blk, 0, stream>>>(fvw2, fvW2t, 2048, 512, 2048, 32, 1, 0L, 0L, 0L);
  transpose_k<1><<<dim3(64, 4), blk, 0, stream>>>(afw,  afW00, 512, 512, 512, 8, 1, 262144L, 0L, 262144L);
  cvt_k<<<2048, blk, 0, stream>>>(x, xbf, 4194304L);

  // ================= Phase A: cross_layer(vis, text, ft) =================
  ln_k<0><<<ceildiv(6272,4), blk, 0, stream>>>(vis, ftln + 0, ftln + 512, bufLN, 6272);
  launch_gemm<0,0,0,128,64,0,0,1>(stream, 49,8,1, bufLN,1,0,0,512, ftWq,1,0,0,512,
      bufQ,1,0,0,512, ftb + 0, nullptr, nullptr, 6272,512,512, 1.f);
  launch_gemm<1,0,0,128,64,0,0,1>(stream, 64,8,1, text,1,0,0,512, ftWk,1,0,0,512,
      bufK,1,0,0,512, ftb + 512, nullptr, nullptr, 8192,512,512, 1.f);
  launch_gemm<1,0,0,128,64,0,0,1>(stream, 64,8,1, text,1,0,0,512, ftWv,1,0,0,512,
      bufV,1,0,0,512, ftb + 1024, nullptr, nullptr, 8192,512,512, 1.f);
  transpose_k<0><<<dim3(4,256), blk, 0, stream>>>(bufV, bufT, 256, 512, 256, 4, 8, 131072L, 64L, 16384L);
  launch_gemm<0,0,0,64,64,0,0,0>(stream, 4,4,256, bufQ,8,100352L,64L,512, bufK,8,131072L,64L,512,
      bufS,1,50176L,0L,256, nullptr, nullptr, nullptr, 196,256,64, 0.125f);
  softmax_k<<<ceildiv(50176,4), blk, 0, stream>>>(bufS, 50176, 256);
  launch_gemm<0,0,0,64,64,0,0,0>(stream, 4,1,256, bufS,1,50176L,0L,256, bufT,1,16384L,0L,256,
      bufO,8,100352L,64L,512, nullptr, nullptr, nullptr, 196,64,256, 1.f);
  launch_gemm<0,0,1,128,64,0,1,1>(stream, 49,8,1, bufO,1,0,0,512, ftWo,1,0,0,512,
      bufX1,1,0,0,512, ftb + 1536, vis, nullptr, 6272,512,512, 1.f);
  ln_k<0><<<ceildiv(6272,4), blk, 0, stream>>>(bufX1, ftln + 1024, ftln + 1536, bufLN, 6272);
  launch_gemm<0,0,0,128,128,1,0,1>(stream, 49,16,1, bufLN,1,0,0,512, ftW1t,1,0,0,512,
      bufS,1,0,0,2048, ftb1, nullptr, nullptr, 6272,2048,512, 1.f);
  launch_gemm<0,0,1,128,64,0,1,1>(stream, 49,8,1, bufS,1,0,0,2048, ftW2t,1,0,0,2048,
      bufX1,1,0,0,512, ftb2, bufX1, nullptr, 6272,512,2048, 1.f);

  // ================= Phase B: cross_layer(med1, vis, fv) + med1 =================
  ln_k<0><<<ceildiv(6272,4), blk, 0, stream>>>(bufX1, fvln + 0, fvln + 512, bufLN, 6272);
  launch_gemm<0,0,0,128,64,0,0,1>(stream, 49,8,1, bufLN,1,0,0,512, fvWq,1,0,0,512,
      bufQ,1,0,0,512, fvb + 0, nullptr, nullptr, 6272,512,512, 1.f);
  launch_gemm<1,0,0,128,64,0,0,1>(stream, 49,8,1, vis,1,0,0,512, fvWk,1,0,0,512,
      bufK,1,0,0,512, fvb + 512, nullptr, nullptr, 6272,512,512, 1.f);
  launch_gemm<1,0,0,128,64,0,0,1>(stream, 49,8,1, vis,1,0,0,512, fvWv,1,0,0,512,
      bufV,1,0,0,512, fvb + 1024, nullptr, nullptr, 6272,512,512, 1.f);
  transpose_k<0><<<dim3(4,256), blk, 0, stream>>>(bufV, bufT, 196, 512, 256, 4, 8, 100352L, 64L, 16384L);
  launch_gemm<0,0,0,64,64,0,0,0>(stream, 4,4,256, bufQ,8,100352L,64L,512, bufK,8,100352L,64L,512,
      bufS,1,50176L,0L,256, nullptr, nullptr, nullptr, 196,196,64, 0.125f);
  softmax_k<<<ceildiv(50176,4), blk, 0, stream>>>(bufS, 50176, 196);
  launch_gemm<0,0,0,64,64,0,0,0>(stream, 4,1,256, bufS,1,50176L,0L,256, bufT,1,16384L,0L,256,
      bufO,8,100352L,64L,512, nullptr, nullptr, nullptr, 196,64,256, 1.f);
  launch_gemm<0,0,1,128,64,0,1,1>(stream, 49,8,1, bufO,1,0,0,512, fvWo,1,0,0,512,
      bufA2,1,0,0,512, fvb + 1536, bufX1, nullptr, 6272,512,512, 1.f);
  ln_k<0><<<ceildiv(6272,4), blk, 0, stream>>>(bufA2, fvln + 1024, fvln + 1536, bufLN, 6272);
  launch_gemm<0,0,0,128,128,1,0,1>(stream, 49,16,1, bufLN,1,0,0,512, fvW1t,1,0,0,512,
      bufS,1,0,0,2048, fvb1, nullptr, nullptr, 6272,2048,512, 1.f);
  launch_gemm<0,0,1,128,64,0,2,1>(stream, 49,8,1, bufS,1,0,0,2048, fvW2t,1,0,0,2048,
      bufA2,1,0,0,512, fvb2, bufA2, bufX1, 6272,512,2048, 1.f);
  ln_k<0><<<ceildiv(6272,4), blk, 0, stream>>>(bufA2, ldmln + 0, ldmln + 512, bufMED, 6272);

  // ================= Phase C: v_af = af(med, x, x) =================
  transpose_k<0><<<dim3(32,32), blk, 0, stream>>>(xbf, bufT, 256, 512, 256, 4, 1, 131072L, 0L, 131072L);
  launch_gemm<0,0,0,128,64,0,0,1>(stream, 49,8,1, bufMED,1,0,0,512, afW00,1,0,0,512,
      bufQ,1,0,0,512, afb + 0, nullptr, nullptr, 6272,512,512, 1.f);
  launch_gemm<0,0,0,64,64,0,0,0>(stream, 4,4,32, bufQ,1,100352L,0L,512, xbf,1,131072L,0L,512,
      bufS,1,50176L,0L,256, nullptr, nullptr, nullptr, 196,256,512, AFS);
  softmax_k<<<ceildiv(6272,4), blk, 0, stream>>>(bufS, 6272, 256);
  launch_gemm<0,0,0,64,64,0,0,0>(stream, 4,8,32, bufS,1,50176L,0L,256, bufT,1,131072L,0L,256,
      bufO,1,100352L,0L,512, nullptr, nullptr, nullptr, 196,512,256, 1.f);
  launch_gemm<0,0,0,128,64,0,0,1>(stream, 49,8,1, bufO,1,0,0,512, afW01,1,0,0,512,
      bufK,1,0,0,512, afb + 512, nullptr, nullptr, 6272,512,512, 1.f);
  transpose_k<0><<<dim3(32,32), blk, 0, stream>>>(bufK, bufT, 196, 512, 256, 4, 1, 100352L, 0L, 131072L);

  // ================= Phase D: out = af(x, med, v_af) + x =================
  launch_gemm<0,0,0,128,64,0,0,1>(stream, 64,8,1, xbf,1,0,0,512, afW10,1,0,0,512,
      bufQ,1,0,0,512, afb + 1024, nullptr, nullptr, 8192,512,512, 1.f);
  launch_gemm<0,0,0,64,64,0,0,0>(stream, 4,4,32, bufQ,1,131072L,0L,512, bufMED,1,100352L,0L,512,
      bufS,1,65536L,0L,256, nullptr, nullptr, nullptr, 256,196,512, AFS);
  softmax_k<<<ceildiv(8192,4), blk, 0, stream>>>(bufS, 8192, 196);
  launch_gemm<0,0,0,64,64,0,0,0>(stream, 4,8,32, bufS,1,65536L,0L,256, bufT,1,131072L,0L,256,
      bufO,1,131072L,0L,512, nullptr, nullptr, nullptr, 256,512,256, 1.f);
  launch_gemm<0,0,1,128,64,0,1,1>(stream, 64,8,1, bufO,1,0,0,512, afW11,1,0,0,512,
      out,1,0,0,512, afb + 1536, x, nullptr, 8192,512,512, 1.f);
}

// Round 3
// 572.602 us; speedup vs baseline: 1.3000x; 1.0612x over previous
//
#include <hip/hip_runtime.h>
#include <hip/hip_bf16.h>

typedef __attribute__((ext_vector_type(4))) float f32x4;
typedef __attribute__((ext_vector_type(8))) short s16x8;
typedef __attribute__((ext_vector_type(4))) short s16x4;

__device__ __forceinline__ short f2bf(float f) {
  union { float f; unsigned u; } c; c.f = f;
  unsigned r = c.u + 0x7fffu + ((c.u >> 16) & 1u);
  return (short)(r >> 16);
}
__device__ __forceinline__ float bf2f(short h) {
  union { unsigned u; float f; } c; c.u = ((unsigned)(unsigned short)h) << 16;
  return c.f;
}
__device__ __forceinline__ s16x8 cvt8(const f32x4& lo, const f32x4& hi) {
  s16x8 v;
  v[0] = f2bf(lo[0]); v[1] = f2bf(lo[1]); v[2] = f2bf(lo[2]); v[3] = f2bf(lo[3]);
  v[4] = f2bf(hi[0]); v[5] = f2bf(hi[1]); v[6] = f2bf(hi[2]); v[7] = f2bf(hi[3]);
  return v;
}

// async global->LDS, 16B per lane (dest = wave-uniform base + lane*16)
__device__ __forceinline__ void gl_lds16(const short* g, char* l) {
  __builtin_amdgcn_global_load_lds(
      (const __attribute__((address_space(1))) unsigned int*)g,
      (__attribute__((address_space(3))) unsigned int*)l, 16, 0, 0);
}

// ---------------------------------------------------------------------------
// MFMA GEMM, all-bf16 operands: C[M,N] = alpha*A[M,K]@B[N,K]^T (+bias)(+res)
// global_load_lds staging, involutive chunk-XOR swizzle:
//   LDS[row][c] holds global chunk (c ^ (row&7)); fragment read re-applies XOR.
// SWZ=1: XCD-chunked bijective block remap.
// ---------------------------------------------------------------------------
template<int CF32, int BM, int BN, int RELU, int NRES, int SWZ>
__global__ __launch_bounds__(256, 2)
void gemm_k(const short* __restrict__ Ap, int hbA, long sAo, long sAi, int lda,
            const short* __restrict__ Bp, int hbB, long sBo, long sBi, int ldb,
            void* __restrict__ Cp, int hbC, long sCo, long sCi, int ldc,
            const float* __restrict__ bias,
            const float* __restrict__ res1,
            const float* __restrict__ res2,
            int M, int N, int K, float alpha)
{
  constexpr int MI = BM / 32, NI = BN / 32;
  constexpr int ACH = BM / 32, BCH = BN / 32;       // 16B chunks per thread
  constexpr int ABYTES = BM * 128;                  // A region per buffer
  constexpr int TBYTES = (BM + BN) * 128;           // per-buffer bytes
  __shared__ __align__(16) char smem[2 * TBYTES];

  const int tid  = threadIdx.x;
  const int lane = tid & 63;
  const int wid  = tid >> 6;
  const int wr   = wid >> 1, wc = wid & 1;
  const int z    = blockIdx.z;

  int bx = blockIdx.x, by = blockIdx.y;
  if constexpr (SWZ) {
    const int gx = gridDim.x, gy = gridDim.y;
    const int nwg = gx * gy;
    const int o = by * gx + bx;
    const int q = nwg >> 3, r = nwg & 7;
    const int xcd = o & 7, slot = o >> 3;
    const int w = (xcd < r ? xcd * (q + 1) : r * (q + 1) + (xcd - r) * q) + slot;
    bx = w / gy; by = w - bx * gy;
  }
  const int m0 = bx * BM, n0 = by * BN;

  const int zA = z / hbA, zAi = z - zA * hbA;
  const int zB = z / hbB, zBi = z - zB * hbB;
  const int zC = z / hbC, zCi = z - zC * hbC;
  const short* Ab = Ap + (long)zA * sAo + (long)zAi * sAi;
  const short* Bb = Bp + (long)zB * sBo + (long)zBi * sBi;
  char*        Cb = (char*)Cp + ((long)zC * sCo + (long)zCi * sCi) * (CF32 ? 4 : 2);

  // staging descriptors: chunk id -> (row, swizzled source chunk)
  int aL[ACH]; long aG[ACH];
#pragma unroll
  for (int j = 0; j < ACH; ++j) {
    int chunk = (j * 4 + wid) * 64 + lane;
    int row = chunk >> 3;
    int c   = (chunk & 7) ^ (row & 7);
    int gr = m0 + row; if (gr > M - 1) gr = M - 1;
    aL[j] = chunk * 16;
    aG[j] = (long)gr * lda + c * 8;
  }
  int bL[BCH]; long bG[BCH];
#pragma unroll
  for (int j = 0; j < BCH; ++j) {
    int chunk = (j * 4 + wid) * 64 + lane;
    int row = chunk >> 3;
    int c   = (chunk & 7) ^ (row & 7);
    int gc = n0 + row; if (gc > N - 1) gc = N - 1;
    bL[j] = chunk * 16;
    bG[j] = (long)gc * ldb + c * 8;
  }

  auto stage = [&](int buf, int kt) {
    const short* Akt = Ab + (long)kt * 64;
    char* base = smem + buf * TBYTES;
#pragma unroll
    for (int j = 0; j < ACH; ++j) gl_lds16(Akt + aG[j], base + aL[j]);
    const short* Bkt = Bb + (long)kt * 64;
#pragma unroll
    for (int j = 0; j < BCH; ++j) gl_lds16(Bkt + bG[j], base + ABYTES + bL[j]);
  };

  // fragment ds_read byte offsets
  int ard[2][MI], brd[2][NI];
#pragma unroll
  for (int kk = 0; kk < 2; ++kk) {
    int kgr = kk * 4 + (lane >> 4);
#pragma unroll
    for (int mi = 0; mi < MI; ++mi) {
      int m = wr * (BM / 2) + mi * 16 + (lane & 15);
      ard[kk][mi] = m * 128 + ((kgr ^ (m & 7)) << 4);
    }
#pragma unroll
    for (int ni = 0; ni < NI; ++ni) {
      int n = wc * (BN / 2) + ni * 16 + (lane & 15);
      brd[kk][ni] = ABYTES + n * 128 + ((kgr ^ (n & 7)) << 4);
    }
  }

  stage(0, 0);
  asm volatile("s_waitcnt vmcnt(0)" ::: "memory");
  __syncthreads();

  f32x4 acc[MI][NI];
#pragma unroll
  for (int mi = 0; mi < MI; ++mi)
#pragma unroll
    for (int ni = 0; ni < NI; ++ni) acc[mi][ni] = (f32x4){0.f, 0.f, 0.f, 0.f};

  const int NT = K >> 6;
  for (int kt = 0; kt < NT; ++kt) {
    const int cur = kt & 1;
    if (kt + 1 < NT) stage(cur ^ 1, kt + 1);

    const char* base = smem + cur * TBYTES;
    s16x8 afr[2][MI], bfr[2][NI];
#pragma unroll
    for (int kk = 0; kk < 2; ++kk) {
#pragma unroll
      for (int mi = 0; mi < MI; ++mi) afr[kk][mi] = *(const s16x8*)(base + ard[kk][mi]);
#pragma unroll
      for (int ni = 0; ni < NI; ++ni) bfr[kk][ni] = *(const s16x8*)(base + brd[kk][ni]);
    }
#pragma unroll
    for (int kk = 0; kk < 2; ++kk)
#pragma unroll
      for (int mi = 0; mi < MI; ++mi)
#pragma unroll
        for (int ni = 0; ni < NI; ++ni)
          acc[mi][ni] = __builtin_amdgcn_mfma_f32_16x16x32_bf16(afr[kk][mi], bfr[kk][ni], acc[mi][ni], 0, 0, 0);

    if (kt + 1 < NT) {
      asm volatile("s_waitcnt vmcnt(0)" ::: "memory");
      __syncthreads();
    }
  }

#pragma unroll
  for (int mi = 0; mi < MI; ++mi) {
#pragma unroll
    for (int ni = 0; ni < NI; ++ni) {
      int col = n0 + wc * (BN / 2) + ni * 16 + (lane & 15);
      if (col < N) {
        float bv = bias ? bias[col] : 0.f;
        int rbase = m0 + wr * (BM / 2) + mi * 16 + ((lane >> 4) << 2);
#pragma unroll
        for (int j = 0; j < 4; ++j) {
          int r = rbase + j;
          if (r < M) {
            float v = acc[mi][ni][j] * alpha + bv;
            if constexpr (NRES >= 1) v += res1[(long)r * ldc + col];
            if constexpr (NRES >= 2) v += res2[(long)r * ldc + col];
            if constexpr (RELU) v = fmaxf(v, 0.f);
            if constexpr (CF32) ((float*)Cb)[(long)r * ldc + col] = v;
            else                ((short*)Cb)[(long)r * ldc + col] = f2bf(v);
          }
        }
      }
    }
  }
}

// ---------------------------------------------------------------------------
// Batched transpose -> bf16 [C x Rpad], zero-pad rows R_in..Rpad-1
// ---------------------------------------------------------------------------
template<int INF32>
__global__ __launch_bounds__(256)
void transpose_k(const void* __restrict__ inp, short* __restrict__ outp,
                 int R_in, int rs_in, int Rpad, int tiles_r,
                 int hb, long sO, long sI, long out_bs)
{
  __shared__ float tile[64][65];
  const int z = blockIdx.y;
  const int zo = z / hb, zi = z - zo * hb;
  const char* in = (const char*)inp + ((long)zo * sO + (long)zi * sI) * (INF32 ? 4 : 2);
  short* out = outp + (long)z * out_bs;
  const int zt = blockIdx.x;
  const int tr = zt % tiles_r, tc = zt / tiles_r;
  const int r0 = tr * 64, c0 = tc * 64;
  const int c = threadIdx.x & 63, l0 = threadIdx.x >> 6;

#pragma unroll 4
  for (int i = 0; i < 16; ++i) {
    int l = l0 + i * 4;
    int gr = r0 + l;
    float v = 0.f;
    if (gr < R_in) {
      long off = (long)gr * rs_in + c0 + c;
      v = INF32 ? ((const float*)in)[off] : bf2f(((const short*)in)[off]);
    }
    tile[l][c] = v;
  }
  __syncthreads();
#pragma unroll 4
  for (int i = 0; i < 16; ++i) {
    int cr = l0 + i * 4;
    out[(long)(c0 + cr) * Rpad + r0 + c] = f2bf(tile[c][cr]);
  }
}

// ---------------------------------------------------------------------------
// fp32 -> bf16 bulk convert (n multiple of 8)
// ---------------------------------------------------------------------------
__global__ __launch_bounds__(256)
void cvt_k(const float* __restrict__ in, short* __restrict__ out, long n)
{
  long i = ((long)blockIdx.x * 256 + threadIdx.x) * 8;
  if (i >= n) return;
  f32x4 a = *(const f32x4*)(in + i), b = *(const f32x4*)(in + i + 4);
  *(s16x8*)(out + i) = cvt8(a, b);
}

// ---------------------------------------------------------------------------
// LayerNorm over D=512, one wave per row; bf16 out
// ---------------------------------------------------------------------------
__global__ __launch_bounds__(256)
void ln_k(const float* __restrict__ in, const float* __restrict__ g,
          const float* __restrict__ b, short* __restrict__ outp, int rows)
{
  int row = blockIdx.x * 4 + (threadIdx.x >> 6);
  if (row >= rows) return;
  int lane = threadIdx.x & 63;
  const float* p = in + (long)row * 512 + lane * 8;
  f32x4 v0 = *(const f32x4*)p, v1 = *(const f32x4*)(p + 4);
  float s = 0.f, sq = 0.f;
#pragma unroll
  for (int j = 0; j < 4; ++j) { s += v0[j] + v1[j]; sq += v0[j]*v0[j] + v1[j]*v1[j]; }
#pragma unroll
  for (int o = 1; o < 64; o <<= 1) { s += __shfl_xor(s, o); sq += __shfl_xor(sq, o); }
  float mean = s * (1.f / 512.f);
  float var  = sq * (1.f / 512.f) - mean * mean;
  float rs   = rsqrtf(var + 1e-6f);
  const f32x4 g0 = *(const f32x4*)(g + lane * 8), g1 = *(const f32x4*)(g + lane * 8 + 4);
  const f32x4 b0 = *(const f32x4*)(b + lane * 8), b1 = *(const f32x4*)(b + lane * 8 + 4);
  f32x4 o0, o1;
#pragma unroll
  for (int j = 0; j < 4; ++j) {
    o0[j] = g0[j] * (v0[j] - mean) * rs + b0[j];
    o1[j] = g1[j] * (v1[j] - mean) * rs + b1[j];
  }
  short* op = outp + (long)row * 512 + lane * 8;
  *(s16x8*)op = cvt8(o0, o1);
}

// ---------------------------------------------------------------------------
// Row softmax over 256 bf16 columns (valid nvalid, rest -> 0), in place.
// ---------------------------------------------------------------------------
__global__ __launch_bounds__(256)
void softmax_k(short* __restrict__ S, int rows, int nvalid)
{
  int row = blockIdx.x * 4 + (threadIdx.x >> 6);
  if (row >= rows) return;
  int lane = threadIdx.x & 63;
  short* p = S + (long)row * 256 + lane * 4;
  s16x4 raw = *(const s16x4*)p;
  float x[4];
#pragma unroll
  for (int j = 0; j < 4; ++j) {
    int col = lane * 4 + j;
    x[j] = (col < nvalid) ? bf2f(raw[j]) : -3.0e38f;
  }
  float m = fmaxf(fmaxf(x[0], x[1]), fmaxf(x[2], x[3]));
#pragma unroll
  for (int o = 1; o < 64; o <<= 1) m = fmaxf(m, __shfl_xor(m, o));
  float e[4]; float s = 0.f;
#pragma unroll
  for (int j = 0; j < 4; ++j) {
    int col = lane * 4 + j;
    e[j] = (col < nvalid) ? __expf(x[j] - m) : 0.f;
    s += e[j];
  }
#pragma unroll
  for (int o = 1; o < 64; o <<= 1) s += __shfl_xor(s, o);
  float inv = 1.f / s;
  s16x4 ov;
#pragma unroll
  for (int j = 0; j < 4; ++j) ov[j] = f2bf(e[j] * inv);
  *(s16x4*)p = ov;
}

// ---------------------------------------------------------------------------
static inline int ceildiv(int a, int b) { return (a + b - 1) / b; }

template<int CF32, int BM, int BN, int RELU, int NRES, int SWZ>
static void launch_gemm(hipStream_t st, int gm, int gn, int gz,
                        const short* A, int hbA, long sAo, long sAi, int lda,
                        const short* B, int hbB, long sBo, long sBi, int ldb,
                        void* C, int hbC, long sCo, long sCi, int ldc,
                        const float* bias, const float* r1, const float* r2,
                        int M, int N, int K, float alpha)
{
  gemm_k<CF32, BM, BN, RELU, NRES, SWZ>
      <<<dim3(gm, gn, gz), dim3(256), 0, st>>>(
          A, hbA, sAo, sAi, lda, B, hbB, sBo, sBi, ldb,
          C, hbC, sCo, sCi, ldc, bias, r1, r2, M, N, K, alpha);
}

extern "C" void kernel_launch(void* const* d_in, const int* in_sizes, int n_in,
                              void* d_out, int out_size, void* d_ws, size_t ws_size,
                              hipStream_t stream)
{
  (void)in_sizes; (void)n_in; (void)out_size; (void)ws_size;

  const float* x     = (const float*)d_in[0];   // [32,256,512]
  const float* text  = (const float*)d_in[1];   // [32,256,512]
  const float* vis   = (const float*)d_in[2];   // [32,196,512]
  const float* ftw   = (const float*)d_in[3];   // [4,512,512]
  const float* ftb   = (const float*)d_in[4];   // [4,512]
  const float* ftw1  = (const float*)d_in[5];   // [512,2048]
  const float* ftb1  = (const float*)d_in[6];
  const float* ftw2  = (const float*)d_in[7];   // [2048,512]
  const float* ftb2  = (const float*)d_in[8];
  const float* ftln  = (const float*)d_in[9];   // [2,2,512]
  const float* fvw   = (const float*)d_in[10];
  const float* fvb   = (const float*)d_in[11];
  const float* fvw1  = (const float*)d_in[12];
  const float* fvb1  = (const float*)d_in[13];
  const float* fvw2  = (const float*)d_in[14];
  const float* fvb2  = (const float*)d_in[15];
  const float* fvln  = (const float*)d_in[16];
  const float* ldmln = (const float*)d_in[17];  // [2,512]
  const float* afw   = (const float*)d_in[18];  // [2,2,512,512]
  const float* afb   = (const float*)d_in[19];  // [2,2,512]
  float* out = (float*)d_out;

  char* ws = (char*)d_ws;
  short* wT     = (short*)ws;                    // 14,680,064 B bf16 weights
  short* xbf    = (short*)(ws + 14680064);       // 8,388,608 B
  short* bufLN  = (short*)(ws + 23068672);       // 6,422,528 B
  short* bufQ   = (short*)(ws + 29491200);       // 8,388,608 B
  short* bufKV  = (short*)(ws + 37879808);       // 16,777,216 B [M][1024]
  short* bufT   = (short*)(ws + 54657024);       // 8,388,608 B
  short* bufS   = (short*)(ws + 63045632);       // 25,690,112 B (scores / hidden)
  short* bufO   = (short*)(ws + 88735744);       // 8,388,608 B (also textbf)
  float* bufX1  = (float*)(ws + 97124352);       // 12,845,056 B fp32
  float* bufA2  = (float*)(ws + 109969408);      // 12,845,056 B fp32 (also visbf)
  short* bufMED = (short*)(ws + 122814464);      // 6,422,528 B
  short* textbf = bufO;                          // dead before bufO first write
  short* visbf  = (short*)bufA2;                 // dead before bufA2 first write

  short* ftWq  = wT + 0;
  short* ftWk  = wT + 262144;   // ftWk..ftWv contiguous = [1024][512]
  short* ftWo  = wT + 786432;
  short* ftW1t = wT + 1048576;
  short* ftW2t = wT + 2097152;
  short* fvWq  = wT + 3145728;
  short* fvWk  = wT + 3407872;  // fvWk..fvWv contiguous
  short* fvWo  = wT + 3932160;
  short* fvW1t = wT + 4194304;
  short* fvW2t = wT + 5242880;
  short* afW00 = wT + 6291456;
  short* afW01 = wT + 6553600;
  short* afW10 = wT + 6815744;
  short* afW11 = wT + 7077888;

  const float AFS = 0.04419417382415922f; // 1/sqrt(512)
  dim3 blk(256);

  // ---- prep ----
  transpose_k<1><<<dim3(64, 4), blk, 0, stream>>>(ftw,  ftWq,  512, 512, 512, 8, 1, 262144L, 0L, 262144L);
  transpose_k<1><<<dim3(256,1), blk, 0, stream>>>(ftw1, ftW1t, 512, 2048, 512, 8, 1, 0L, 0L, 0L);
  transpose_k<1><<<dim3(256,1), blk, 0, stream>>>(ftw2, ftW2t, 2048, 512, 2048, 32, 1, 0L, 0L, 0L);
  transpose_k<1><<<dim3(64, 4), blk, 0, stream>>>(fvw,  fvWq,  512, 512, 512, 8, 1, 262144L, 0L, 262144L);
  transpose_k<1><<<dim3(256,1), blk, 0, stream>>>(fvw1, fvW1t, 512, 2048, 512, 8, 1, 0L, 0L, 0L);
  transpose_k<1><<<dim3(256,1), blk, 0, stream>>>(fvw2, fvW2t, 2048, 512, 2048, 32, 1, 0L, 0L, 0L);
  transpose_k<1><<<dim3(64, 4), blk, 0, stream>>>(afw,  afW00, 512, 512, 512, 8, 1, 262144L, 0L, 262144L);
  cvt_k<<<2048, blk, 0, stream>>>(x, xbf, 4194304L);
  cvt_k<<<2048, blk, 0, stream>>>(text, textbf, 4194304L);
  cvt_k<<<1568, blk, 0, stream>>>(vis, visbf, 3211264L);

  // ================= Phase A: cross_layer(vis, text, ft) =================
  ln_k<<<1568, blk, 0, stream>>>(vis, ftln + 0, ftln + 512, bufLN, 6272);
  launch_gemm<0,128,64,0,0,1>(stream, 49,8,1, bufLN,1,0,0,512, ftWq,1,0,0,512,
      bufQ,1,0,0,512, ftb + 0, nullptr, nullptr, 6272,512,512, 1.f);
  launch_gemm<0,128,64,0,0,1>(stream, 64,16,1, textbf,1,0,0,512, ftWk,1,0,0,512,
      bufKV,1,0,0,1024, ftb + 512, nullptr, nullptr, 8192,1024,512, 1.f);
  transpose_k<0><<<dim3(4,256), blk, 0, stream>>>(bufKV + 512, bufT, 256, 1024, 256, 4, 8, 262144L, 64L, 16384L);
  launch_gemm<0,64,64,0,0,0>(stream, 4,4,256, bufQ,8,100352L,64L,512, bufKV,8,262144L,64L,1024,
      bufS,1,50176L,0L,256, nullptr, nullptr, nullptr, 196,256,64, 0.125f);
  softmax_k<<<ceildiv(50176,4), blk, 0, stream>>>(bufS, 50176, 256);
  launch_gemm<0,64,64,0,0,0>(stream, 4,1,256, bufS,1,50176L,0L,256, bufT,1,16384L,0L,256,
      bufO,8,100352L,64L,512, nullptr, nullptr, nullptr, 196,64,256, 1.f);
  launch_gemm<1,128,64,0,1,1>(stream, 49,8,1, bufO,1,0,0,512, ftWo,1,0,0,512,
      bufX1,1,0,0,512, ftb + 1536, vis, nullptr, 6272,512,512, 1.f);
  ln_k<<<1568, blk, 0, stream>>>(bufX1, ftln + 1024, ftln + 1536, bufLN, 6272);
  launch_gemm<0,128,128,1,0,1>(stream, 49,16,1, bufLN,1,0,0,512, ftW1t,1,0,0,512,
      bufS,1,0,0,2048, ftb1, nullptr, nullptr, 6272,2048,512, 1.f);
  launch_gemm<1,128,64,0,1,1>(stream, 49,8,1, bufS,1,0,0,2048, ftW2t,1,0,0,2048,
      bufX1,1,0,0,512, ftb2, bufX1, nullptr, 6272,512,2048, 1.f);

  // ================= Phase B: cross_layer(med1, vis, fv) + med1 =================
  ln_k<<<1568, blk, 0, stream>>>(bufX1, fvln + 0, fvln + 512, bufLN, 6272);
  launch_gemm<0,128,64,0,0,1>(stream, 49,8,1, bufLN,1,0,0,512, fvWq,1,0,0,512,
      bufQ,1,0,0,512, fvb + 0, nullptr, nullptr, 6272,512,512, 1.f);
  launch_gemm<0,128,64,0,0,1>(stream, 49,16,1, visbf,1,0,0,512, fvWk,1,0,0,512,
      bufKV,1,0,0,1024, fvb + 512, nullptr, nullptr, 6272,1024,512, 1.f);
  transpose_k<0><<<dim3(4,256), blk, 0, stream>>>(bufKV + 512, bufT, 196, 1024, 256, 4, 8, 200704L, 64L, 16384L);
  launch_gemm<0,64,64,0,0,0>(stream, 4,4,256, bufQ,8,100352L,64L,512, bufKV,8,200704L,64L,1024,
      bufS,1,50176L,0L,256, nullptr, nullptr, nullptr, 196,196,64, 0.125f);
  softmax_k<<<ceildiv(50176,4), blk, 0, stream>>>(bufS, 50176, 196);
  launch_gemm<0,64,64,0,0,0>(stream, 4,1,256, bufS,1,50176L,0L,256, bufT,1,16384L,0L,256,
      bufO,8,100352L,64L,512, nullptr, nullptr, nullptr, 196,64,256, 1.f);
  launch_gemm<1,128,64,0,1,1>(stream, 49,8,1, bufO,1,0,0,512, fvWo,1,0,0,512,
      bufA2,1,0,0,512, fvb + 1536, bufX1, nullptr, 6272,512,512, 1.f);
  ln_k<<<1568, blk, 0, stream>>>(bufA2, fvln + 1024, fvln + 1536, bufLN, 6272);
  launch_gemm<0,128,128,1,0,1>(stream, 49,16,1, bufLN,1,0,0,512, fvW1t,1,0,0,512,
      bufS,1,0,0,2048, fvb1, nullptr, nullptr, 6272,2048,512, 1.f);
  launch_gemm<1,128,64,0,2,1>(stream, 49,8,1, bufS,1,0,0,2048, fvW2t,1,0,0,2048,
      bufA2,1,0,0,512, fvb2, bufA2, bufX1, 6272,512,2048, 1.f);
  ln_k<<<1568, blk, 0, stream>>>(bufA2, ldmln + 0, ldmln + 512, bufMED, 6272);

  // ================= Phase C: v_af = af(med, x, x) =================
  transpose_k<0><<<dim3(32,32), blk, 0, stream>>>(xbf, bufT, 256, 512, 256, 4, 1, 131072L, 0L, 131072L);
  launch_gemm<0,128,64,0,0,1>(stream, 49,8,1, bufMED,1,0,0,512, afW00,1,0,0,512,
      bufQ,1,0,0,512, afb + 0, nullptr, nullptr, 6272,512,512, 1.f);
  launch_gemm<0,64,64,0,0,0>(stream, 4,4,32, bufQ,1,100352L,0L,512, xbf,1,131072L,0L,512,
      bufS,1,50176L,0L,256, nullptr, nullptr, nullptr, 196,256,512, AFS);
  softmax_k<<<ceildiv(6272,4), blk, 0, stream>>>(bufS, 6272, 256);
  launch_gemm<0,64,64,0,0,0>(stream, 4,8,32, bufS,1,50176L,0L,256, bufT,1,131072L,0L,256,
      bufO,1,100352L,0L,512, nullptr, nullptr, nullptr, 196,512,256, 1.f);
  launch_gemm<0,128,64,0,0,1>(stream, 49,8,1, bufO,1,0,0,512, afW01,1,0,0,512,
      bufKV,1,0,0,512, afb + 512, nullptr, nullptr, 6272,512,512, 1.f);
  transpose_k<0><<<dim3(32,32), blk, 0, stream>>>(bufKV, bufT, 196, 512, 256, 4, 1, 100352L, 0L, 131072L);

  // ================= Phase D: out = af(x, med, v_af) + x =================
  launch_gemm<0,128,64,0,0,1>(stream, 64,8,1, xbf,1,0,0,512, afW10,1,0,0,512,
      bufQ,1,0,0,512, afb + 1024, nullptr, nullptr, 8192,512,512, 1.f);
  launch_gemm<0,64,64,0,0,0>(stream, 4,4,32, bufQ,1,131072L,0L,512, bufMED,1,100352L,0L,512,
      bufS,1,65536L,0L,256, nullptr, nullptr, nullptr, 256,196,512, AFS);
  softmax_k<<<ceildiv(8192,4), blk, 0, stream>>>(bufS, 8192, 196);
  launch_gemm<0,64,64,0,0,0>(stream, 4,8,32, bufS,1,65536L,0L,256, bufT,1,131072L,0L,256,
      bufO,1,131072L,0L,512, nullptr, nullptr, nullptr, 256,512,256, 1.f);
  launch_gemm<1,128,64,0,1,1>(stream, 64,8,1, bufO,1,0,0,512, afW11,1,0,0,512,
      out,1,0,0,512, afb + 1536, x, nullptr, 8192,512,512, 1.f);
}

// Round 4
// 502.028 us; speedup vs baseline: 1.4827x; 1.1406x over previous
//
#include <hip/hip_runtime.h>
#include <hip/hip_bf16.h>

typedef __attribute__((ext_vector_type(4))) float f32x4;
typedef __attribute__((ext_vector_type(8))) short s16x8;
typedef __attribute__((ext_vector_type(4))) short s16x4;

__device__ __forceinline__ short f2bf(float f) {
  union { float f; unsigned u; } c; c.f = f;
  unsigned r = c.u + 0x7fffu + ((c.u >> 16) & 1u);
  return (short)(r >> 16);
}
__device__ __forceinline__ float bf2f(short h) {
  union { unsigned u; float f; } c; c.u = ((unsigned)(unsigned short)h) << 16;
  return c.f;
}
__device__ __forceinline__ s16x8 cvt8(const f32x4& lo, const f32x4& hi) {
  s16x8 v;
  v[0] = f2bf(lo[0]); v[1] = f2bf(lo[1]); v[2] = f2bf(lo[2]); v[3] = f2bf(lo[3]);
  v[4] = f2bf(hi[0]); v[5] = f2bf(hi[1]); v[6] = f2bf(hi[2]); v[7] = f2bf(hi[3]);
  return v;
}

// async global->LDS, 16B per lane (dest = wave-uniform base + lane*16)
__device__ __forceinline__ void gl_lds16(const short* g, char* l) {
  __builtin_amdgcn_global_load_lds(
      (const __attribute__((address_space(1))) unsigned int*)g,
      (__attribute__((address_space(3))) unsigned int*)l, 16, 0, 0);
}

// ---------------------------------------------------------------------------
// MFMA GEMM, all-bf16 operands: C[M,N] = alpha*A[M,K]@B[N,K]^T (+bias)(+res)
// 3-buffer LDS ring, counted vmcnt (never 0 in steady state), raw s_barrier.
// Involutive chunk-XOR LDS swizzle; coalesced LDS-staged epilogue.
// ---------------------------------------------------------------------------
template<int CF32, int BM, int BN, int RELU, int NRES, int SWZ>
__global__ __launch_bounds__(256, 2)
void gemm_k(const short* __restrict__ Ap, int hbA, long sAo, long sAi, int lda,
            const short* __restrict__ Bp, int hbB, long sBo, long sBi, int ldb,
            void* __restrict__ Cp, int hbC, long sCo, long sCi, int ldc,
            const float* __restrict__ bias,
            const float* __restrict__ res1,
            const float* __restrict__ res2,
            int M, int N, int K, float alpha)
{
  constexpr int MI = BM / 32, NI = BN / 32;
  constexpr int ACH = BM / 32, BCH = BN / 32;       // 16B staging insts/wave
  constexpr int L   = ACH + BCH;                    // vmem insts per stage
  constexpr int ABYTES = BM * 128;
  constexpr int TBYTES = (BM + BN) * 128;
  __shared__ __align__(16) char smem[3 * TBYTES];

  const int tid  = threadIdx.x;
  const int lane = tid & 63;
  const int wid  = tid >> 6;
  const int wr   = wid >> 1, wc = wid & 1;
  const int z    = blockIdx.z;

  int bx = blockIdx.x, by = blockIdx.y;
  if constexpr (SWZ) {
    const int gx = gridDim.x, gy = gridDim.y;
    const int nwg = gx * gy;
    const int o = by * gx + bx;
    const int q = nwg >> 3, r = nwg & 7;
    const int xcd = o & 7, slot = o >> 3;
    const int w = (xcd < r ? xcd * (q + 1) : r * (q + 1) + (xcd - r) * q) + slot;
    bx = w / gy; by = w - bx * gy;
  }
  const int m0 = bx * BM, n0 = by * BN;

  const int zA = z / hbA, zAi = z - zA * hbA;
  const int zB = z / hbB, zBi = z - zB * hbB;
  const int zC = z / hbC, zCi = z - zC * hbC;
  const short* Ab = Ap + (long)zA * sAo + (long)zAi * sAi;
  const short* Bb = Bp + (long)zB * sBo + (long)zBi * sBi;
  char*        Cb = (char*)Cp + ((long)zC * sCo + (long)zCi * sCi) * (CF32 ? 4 : 2);

  // staging descriptors
  int aL[ACH]; long aG[ACH];
#pragma unroll
  for (int j = 0; j < ACH; ++j) {
    int chunk = (j * 4 + wid) * 64 + lane;
    int row = chunk >> 3;
    int c   = (chunk & 7) ^ (row & 7);
    int gr = m0 + row; if (gr > M - 1) gr = M - 1;
    aL[j] = chunk * 16;
    aG[j] = (long)gr * lda + c * 8;
  }
  int bL[BCH]; long bG[BCH];
#pragma unroll
  for (int j = 0; j < BCH; ++j) {
    int chunk = (j * 4 + wid) * 64 + lane;
    int row = chunk >> 3;
    int c   = (chunk & 7) ^ (row & 7);
    int gc = n0 + row; if (gc > N - 1) gc = N - 1;
    bL[j] = chunk * 16;
    bG[j] = (long)gc * ldb + c * 8;
  }

  auto stage = [&](int buf, int kt) {
    const short* Akt = Ab + (long)kt * 64;
    char* base = smem + buf * TBYTES;
#pragma unroll
    for (int j = 0; j < ACH; ++j) gl_lds16(Akt + aG[j], base + aL[j]);
    const short* Bkt = Bb + (long)kt * 64;
#pragma unroll
    for (int j = 0; j < BCH; ++j) gl_lds16(Bkt + bG[j], base + ABYTES + bL[j]);
  };

  // fragment ds_read byte offsets
  int ard[2][MI], brd[2][NI];
#pragma unroll
  for (int kk = 0; kk < 2; ++kk) {
    int kgr = kk * 4 + (lane >> 4);
#pragma unroll
    for (int mi = 0; mi < MI; ++mi) {
      int m = wr * (BM / 2) + mi * 16 + (lane & 15);
      ard[kk][mi] = m * 128 + ((kgr ^ (m & 7)) << 4);
    }
#pragma unroll
    for (int ni = 0; ni < NI; ++ni) {
      int n = wc * (BN / 2) + ni * 16 + (lane & 15);
      brd[kk][ni] = ABYTES + n * 128 + ((kgr ^ (n & 7)) << 4);
    }
  }

  const int NT = K >> 6;
  if (0 < NT) stage(0, 0);
  if (1 < NT) stage(1, 1);
  if (2 < NT) stage(2, 2);

  f32x4 acc[MI][NI];
#pragma unroll
  for (int mi = 0; mi < MI; ++mi)
#pragma unroll
    for (int ni = 0; ni < NI; ++ni) acc[mi][ni] = (f32x4){0.f, 0.f, 0.f, 0.f};

  for (int t = 0; t < NT; ++t) {
    const int rem = NT - t;
    if (rem >= 3)      asm volatile("s_waitcnt vmcnt(%0)" :: "n"(2 * L) : "memory");
    else if (rem == 2) asm volatile("s_waitcnt vmcnt(%0)" :: "n"(L) : "memory");
    else               asm volatile("s_waitcnt vmcnt(0)" ::: "memory");
    asm volatile("s_barrier" ::: "memory");

    const char* base = smem + (t % 3) * TBYTES;
    s16x8 afr[2][MI], bfr[2][NI];
#pragma unroll
    for (int kk = 0; kk < 2; ++kk) {
#pragma unroll
      for (int mi = 0; mi < MI; ++mi) afr[kk][mi] = *(const s16x8*)(base + ard[kk][mi]);
#pragma unroll
      for (int ni = 0; ni < NI; ++ni) bfr[kk][ni] = *(const s16x8*)(base + brd[kk][ni]);
    }
#pragma unroll
    for (int kk = 0; kk < 2; ++kk)
#pragma unroll
      for (int mi = 0; mi < MI; ++mi)
#pragma unroll
        for (int ni = 0; ni < NI; ++ni)
          acc[mi][ni] = __builtin_amdgcn_mfma_f32_16x16x32_bf16(afr[kk][mi], bfr[kk][ni], acc[mi][ni], 0, 0, 0);

    if (t + 3 < NT) {
      asm volatile("s_waitcnt lgkmcnt(0)" ::: "memory");
      asm volatile("s_barrier" ::: "memory");
      stage((t + 3) % 3, t + 3);
    }
  }

  // ---------------- epilogue: acc -> LDS -> coalesced global ----------------
  asm volatile("s_waitcnt lgkmcnt(0)" ::: "memory");
  __syncthreads();

  constexpr int LSTR = BN + (CF32 ? 4 : 8);   // padded row stride (elems)
  {
    float* lf = (float*)smem;
    short* lh = (short*)smem;
#pragma unroll
    for (int mi = 0; mi < MI; ++mi)
#pragma unroll
      for (int ni = 0; ni < NI; ++ni) {
        int c_loc = wc * (BN / 2) + ni * 16 + (lane & 15);
        float bv = bias ? bias[n0 + c_loc] : 0.f;
        int rb = wr * (BM / 2) + mi * 16 + ((lane >> 4) << 2);
#pragma unroll
        for (int j = 0; j < 4; ++j) {
          float v = acc[mi][ni][j] * alpha + bv;
          if constexpr (CF32) lf[(rb + j) * LSTR + c_loc] = v;
          else                lh[(rb + j) * LSTR + c_loc] = f2bf(v);
        }
      }
  }
  __syncthreads();

  constexpr int CPR = BN / 8;        // 8-col chunks per row
  constexpr int RP  = 256 / CPR;     // rows per pass
  const int rr0 = tid / CPR;
  const int cc  = (tid % CPR) * 8;
  for (int r = rr0; r < BM; r += RP) {
    const int gr = m0 + r;
    if (gr >= M) break;
    f32x4 a, b;
    if constexpr (CF32) {
      a = *(const f32x4*)((const float*)smem + (long)r * LSTR + cc);
      b = *(const f32x4*)((const float*)smem + (long)r * LSTR + cc + 4);
    } else {
      s16x8 h = *(const s16x8*)((const short*)smem + (long)r * LSTR + cc);
#pragma unroll
      for (int j = 0; j < 4; ++j) { a[j] = bf2f(h[j]); b[j] = bf2f(h[j + 4]); }
    }
    const long gb = (long)gr * ldc + n0 + cc;
    if constexpr (NRES >= 1) {
      f32x4 r1 = *(const f32x4*)(res1 + gb), r2 = *(const f32x4*)(res1 + gb + 4);
#pragma unroll
      for (int j = 0; j < 4; ++j) { a[j] += r1[j]; b[j] += r2[j]; }
    }
    if constexpr (NRES >= 2) {
      f32x4 r1 = *(const f32x4*)(res2 + gb), r2 = *(const f32x4*)(res2 + gb + 4);
#pragma unroll
      for (int j = 0; j < 4; ++j) { a[j] += r1[j]; b[j] += r2[j]; }
    }
    if constexpr (RELU) {
#pragma unroll
      for (int j = 0; j < 4; ++j) { a[j] = fmaxf(a[j], 0.f); b[j] = fmaxf(b[j], 0.f); }
    }
    if constexpr (CF32) {
      *(f32x4*)((float*)Cb + gb) = a;
      *(f32x4*)((float*)Cb + gb + 4) = b;
    } else {
      *(s16x8*)((short*)Cb + gb) = cvt8(a, b);
    }
  }
}

// ---------------------------------------------------------------------------
// Batched transpose -> bf16 [C x Rpad], zero-pad rows R_in..Rpad-1
// ---------------------------------------------------------------------------
template<int INF32>
__global__ __launch_bounds__(256)
void transpose_k(const void* __restrict__ inp, short* __restrict__ outp,
                 int R_in, int rs_in, int Rpad, int tiles_r,
                 int hb, long sO, long sI, long out_bs)
{
  __shared__ float tile[64][65];
  const int z = blockIdx.y;
  const int zo = z / hb, zi = z - zo * hb;
  const char* in = (const char*)inp + ((long)zo * sO + (long)zi * sI) * (INF32 ? 4 : 2);
  short* out = outp + (long)z * out_bs;
  const int zt = blockIdx.x;
  const int tr = zt % tiles_r, tc = zt / tiles_r;
  const int r0 = tr * 64, c0 = tc * 64;
  const int c = threadIdx.x & 63, l0 = threadIdx.x >> 6;

#pragma unroll 4
  for (int i = 0; i < 16; ++i) {
    int l = l0 + i * 4;
    int gr = r0 + l;
    float v = 0.f;
    if (gr < R_in) {
      long off = (long)gr * rs_in + c0 + c;
      v = INF32 ? ((const float*)in)[off] : bf2f(((const short*)in)[off]);
    }
    tile[l][c] = v;
  }
  __syncthreads();
#pragma unroll 4
  for (int i = 0; i < 16; ++i) {
    int cr = l0 + i * 4;
    out[(long)(c0 + cr) * Rpad + r0 + c] = f2bf(tile[c][cr]);
  }
}

// ---------------------------------------------------------------------------
__global__ __launch_bounds__(256)
void cvt_k(const float* __restrict__ in, short* __restrict__ out, long n)
{
  long i = ((long)blockIdx.x * 256 + threadIdx.x) * 8;
  if (i >= n) return;
  f32x4 a = *(const f32x4*)(in + i), b = *(const f32x4*)(in + i + 4);
  *(s16x8*)(out + i) = cvt8(a, b);
}

// ---------------------------------------------------------------------------
// LayerNorm over D=512, one wave per row; bf16 out
// ---------------------------------------------------------------------------
__global__ __launch_bounds__(256)
void ln_k(const float* __restrict__ in, const float* __restrict__ g,
          const float* __restrict__ b, short* __restrict__ outp, int rows)
{
  int row = blockIdx.x * 4 + (threadIdx.x >> 6);
  if (row >= rows) return;
  int lane = threadIdx.x & 63;
  const float* p = in + (long)row * 512 + lane * 8;
  f32x4 v0 = *(const f32x4*)p, v1 = *(const f32x4*)(p + 4);
  float s = 0.f, sq = 0.f;
#pragma unroll
  for (int j = 0; j < 4; ++j) { s += v0[j] + v1[j]; sq += v0[j]*v0[j] + v1[j]*v1[j]; }
#pragma unroll
  for (int o = 1; o < 64; o <<= 1) { s += __shfl_xor(s, o); sq += __shfl_xor(sq, o); }
  float mean = s * (1.f / 512.f);
  float var  = sq * (1.f / 512.f) - mean * mean;
  float rs   = rsqrtf(var + 1e-6f);
  const f32x4 g0 = *(const f32x4*)(g + lane * 8), g1 = *(const f32x4*)(g + lane * 8 + 4);
  const f32x4 b0 = *(const f32x4*)(b + lane * 8), b1 = *(const f32x4*)(b + lane * 8 + 4);
  f32x4 o0, o1;
#pragma unroll
  for (int j = 0; j < 4; ++j) {
    o0[j] = g0[j] * (v0[j] - mean) * rs + b0[j];
    o1[j] = g1[j] * (v1[j] - mean) * rs + b1[j];
  }
  short* op = outp + (long)row * 512 + lane * 8;
  *(s16x8*)op = cvt8(o0, o1);
}

// ---------------------------------------------------------------------------
// Row softmax over 256 bf16 columns (valid nvalid, rest -> 0), in place.
// ---------------------------------------------------------------------------
__global__ __launch_bounds__(256)
void softmax_k(short* __restrict__ S, int rows, int nvalid)
{
  int row = blockIdx.x * 4 + (threadIdx.x >> 6);
  if (row >= rows) return;
  int lane = threadIdx.x & 63;
  short* p = S + (long)row * 256 + lane * 4;
  s16x4 raw = *(const s16x4*)p;
  float x[4];
#pragma unroll
  for (int j = 0; j < 4; ++j) {
    int col = lane * 4 + j;
    x[j] = (col < nvalid) ? bf2f(raw[j]) : -3.0e38f;
  }
  float m = fmaxf(fmaxf(x[0], x[1]), fmaxf(x[2], x[3]));
#pragma unroll
  for (int o = 1; o < 64; o <<= 1) m = fmaxf(m, __shfl_xor(m, o));
  float e[4]; float s = 0.f;
#pragma unroll
  for (int j = 0; j < 4; ++j) {
    int col = lane * 4 + j;
    e[j] = (col < nvalid) ? __expf(x[j] - m) : 0.f;
    s += e[j];
  }
#pragma unroll
  for (int o = 1; o < 64; o <<= 1) s += __shfl_xor(s, o);
  float inv = 1.f / s;
  s16x4 ov;
#pragma unroll
  for (int j = 0; j < 4; ++j) ov[j] = f2bf(e[j] * inv);
  *(s16x4*)p = ov;
}

// ---------------------------------------------------------------------------
static inline int ceildiv(int a, int b) { return (a + b - 1) / b; }

template<int CF32, int BM, int BN, int RELU, int NRES, int SWZ>
static void launch_gemm(hipStream_t st, int gm, int gn, int gz,
                        const short* A, int hbA, long sAo, long sAi, int lda,
                        const short* B, int hbB, long sBo, long sBi, int ldb,
                        void* C, int hbC, long sCo, long sCi, int ldc,
                        const float* bias, const float* r1, const float* r2,
                        int M, int N, int K, float alpha)
{
  gemm_k<CF32, BM, BN, RELU, NRES, SWZ>
      <<<dim3(gm, gn, gz), dim3(256), 0, st>>>(
          A, hbA, sAo, sAi, lda, B, hbB, sBo, sBi, ldb,
          C, hbC, sCo, sCi, ldc, bias, r1, r2, M, N, K, alpha);
}

extern "C" void kernel_launch(void* const* d_in, const int* in_sizes, int n_in,
                              void* d_out, int out_size, void* d_ws, size_t ws_size,
                              hipStream_t stream)
{
  (void)in_sizes; (void)n_in; (void)out_size; (void)ws_size;

  const float* x     = (const float*)d_in[0];   // [32,256,512]
  const float* text  = (const float*)d_in[1];   // [32,256,512]
  const float* vis   = (const float*)d_in[2];   // [32,196,512]
  const float* ftw   = (const float*)d_in[3];   // [4,512,512]
  const float* ftb   = (const float*)d_in[4];   // [4,512]
  const float* ftw1  = (const float*)d_in[5];   // [512,2048]
  const float* ftb1  = (const float*)d_in[6];
  const float* ftw2  = (const float*)d_in[7];   // [2048,512]
  const float* ftb2  = (const float*)d_in[8];
  const float* ftln  = (const float*)d_in[9];   // [2,2,512]
  const float* fvw   = (const float*)d_in[10];
  const float* fvb   = (const float*)d_in[11];
  const float* fvw1  = (const float*)d_in[12];
  const float* fvb1  = (const float*)d_in[13];
  const float* fvw2  = (const float*)d_in[14];
  const float* fvb2  = (const float*)d_in[15];
  const float* fvln  = (const float*)d_in[16];
  const float* ldmln = (const float*)d_in[17];  // [2,512]
  const float* afw   = (const float*)d_in[18];  // [2,2,512,512]
  const float* afb   = (const float*)d_in[19];  // [2,2,512]
  float* out = (float*)d_out;

  char* ws = (char*)d_ws;
  short* wT     = (short*)ws;                    // 14,680,064 B bf16 weights
  short* xbf    = (short*)(ws + 14680064);       // 8,388,608 B
  short* bufLN  = (short*)(ws + 23068672);       // 6,422,528 B
  short* bufQ   = (short*)(ws + 29491200);       // 8,388,608 B
  short* bufKV  = (short*)(ws + 37879808);       // 16,777,216 B [M][1024]
  short* bufT   = (short*)(ws + 54657024);       // 8,388,608 B
  short* bufS   = (short*)(ws + 63045632);       // 25,690,112 B (scores / hidden)
  short* bufO   = (short*)(ws + 88735744);       // 8,388,608 B (also textbf)
  float* bufX1  = (float*)(ws + 97124352);       // 12,845,056 B fp32
  float* bufA2  = (float*)(ws + 109969408);      // 12,845,056 B fp32 (also visbf)
  short* bufMED = (short*)(ws + 122814464);      // 6,422,528 B
  short* textbf = bufO;                          // dead before bufO first write
  short* visbf  = (short*)bufA2;                 // dead before bufA2 first write

  short* ftWq  = wT + 0;
  short* ftWk  = wT + 262144;   // ftWk..ftWv contiguous = [1024][512]
  short* ftWo  = wT + 786432;
  short* ftW1t = wT + 1048576;
  short* ftW2t = wT + 2097152;
  short* fvWq  = wT + 3145728;
  short* fvWk  = wT + 3407872;  // fvWk..fvWv contiguous
  short* fvWo  = wT + 3932160;
  short* fvW1t = wT + 4194304;
  short* fvW2t = wT + 5242880;
  short* afW00 = wT + 6291456;
  short* afW01 = wT + 6553600;
  short* afW10 = wT + 6815744;
  short* afW11 = wT + 7077888;

  const float AFS = 0.04419417382415922f; // 1/sqrt(512)
  dim3 blk(256);

  // ---- prep ----
  transpose_k<1><<<dim3(64, 4), blk, 0, stream>>>(ftw,  ftWq,  512, 512, 512, 8, 1, 262144L, 0L, 262144L);
  transpose_k<1><<<dim3(256,1), blk, 0, stream>>>(ftw1, ftW1t, 512, 2048, 512, 8, 1, 0L, 0L, 0L);
  transpose_k<1><<<dim3(256,1), blk, 0, stream>>>(ftw2, ftW2t, 2048, 512, 2048, 32, 1, 0L, 0L, 0L);
  transpose_k<1><<<dim3(64, 4), blk, 0, stream>>>(fvw,  fvWq,  512, 512, 512, 8, 1, 262144L, 0L, 262144L);
  transpose_k<1><<<dim3(256,1), blk, 0, stream>>>(fvw1, fvW1t, 512, 2048, 512, 8, 1, 0L, 0L, 0L);
  transpose_k<1><<<dim3(256,1), blk, 0, stream>>>(fvw2, fvW2t, 2048, 512, 2048, 32, 1, 0L, 0L, 0L);
  transpose_k<1><<<dim3(64, 4), blk, 0, stream>>>(afw,  afW00, 512, 512, 512, 8, 1, 262144L, 0L, 262144L);
  cvt_k<<<2048, blk, 0, stream>>>(x, xbf, 4194304L);
  cvt_k<<<2048, blk, 0, stream>>>(text, textbf, 4194304L);
  cvt_k<<<1568, blk, 0, stream>>>(vis, visbf, 3211264L);

  // ================= Phase A: cross_layer(vis, text, ft) =================
  ln_k<<<1568, blk, 0, stream>>>(vis, ftln + 0, ftln + 512, bufLN, 6272);
  launch_gemm<0,128,64,0,0,1>(stream, 49,8,1, bufLN,1,0,0,512, ftWq,1,0,0,512,
      bufQ,1,0,0,512, ftb + 0, nullptr, nullptr, 6272,512,512, 1.f);
  launch_gemm<0,128,64,0,0,1>(stream, 64,16,1, textbf,1,0,0,512, ftWk,1,0,0,512,
      bufKV,1,0,0,1024, ftb + 512, nullptr, nullptr, 8192,1024,512, 1.f);
  transpose_k<0><<<dim3(4,256), blk, 0, stream>>>(bufKV + 512, bufT, 256, 1024, 256, 4, 8, 262144L, 64L, 16384L);
  launch_gemm<0,64,64,0,0,0>(stream, 4,4,256, bufQ,8,100352L,64L,512, bufKV,8,262144L,64L,1024,
      bufS,1,50176L,0L,256, nullptr, nullptr, nullptr, 196,256,64, 0.125f);
  softmax_k<<<ceildiv(50176,4), blk, 0, stream>>>(bufS, 50176, 256);
  launch_gemm<0,64,64,0,0,0>(stream, 4,1,256, bufS,1,50176L,0L,256, bufT,1,16384L,0L,256,
      bufO,8,100352L,64L,512, nullptr, nullptr, nullptr, 196,64,256, 1.f);
  launch_gemm<1,128,64,0,1,1>(stream, 49,8,1, bufO,1,0,0,512, ftWo,1,0,0,512,
      bufX1,1,0,0,512, ftb + 1536, vis, nullptr, 6272,512,512, 1.f);
  ln_k<<<1568, blk, 0, stream>>>(bufX1, ftln + 1024, ftln + 1536, bufLN, 6272);
  launch_gemm<0,128,64,1,0,1>(stream, 49,32,1, bufLN,1,0,0,512, ftW1t,1,0,0,512,
      bufS,1,0,0,2048, ftb1, nullptr, nullptr, 6272,2048,512, 1.f);
  launch_gemm<1,128,64,0,1,1>(stream, 49,8,1, bufS,1,0,0,2048, ftW2t,1,0,0,2048,
      bufX1,1,0,0,512, ftb2, bufX1, nullptr, 6272,512,2048, 1.f);

  // ================= Phase B: cross_layer(med1, vis, fv) + med1 =================
  ln_k<<<1568, blk, 0, stream>>>(bufX1, fvln + 0, fvln + 512, bufLN, 6272);
  launch_gemm<0,128,64,0,0,1>(stream, 49,8,1, bufLN,1,0,0,512, fvWq,1,0,0,512,
      bufQ,1,0,0,512, fvb + 0, nullptr, nullptr, 6272,512,512, 1.f);
  launch_gemm<0,128,64,0,0,1>(stream, 49,16,1, visbf,1,0,0,512, fvWk,1,0,0,512,
      bufKV,1,0,0,1024, fvb + 512, nullptr, nullptr, 6272,1024,512, 1.f);
  transpose_k<0><<<dim3(4,256), blk, 0, stream>>>(bufKV + 512, bufT, 196, 1024, 256, 4, 8, 200704L, 64L, 16384L);
  launch_gemm<0,64,64,0,0,0>(stream, 4,4,256, bufQ,8,100352L,64L,512, bufKV,8,200704L,64L,1024,
      bufS,1,50176L,0L,256, nullptr, nullptr, nullptr, 196,196,64, 0.125f);
  softmax_k<<<ceildiv(50176,4), blk, 0, stream>>>(bufS, 50176, 196);
  launch_gemm<0,64,64,0,0,0>(stream, 4,1,256, bufS,1,50176L,0L,256, bufT,1,16384L,0L,256,
      bufO,8,100352L,64L,512, nullptr, nullptr, nullptr, 196,64,256, 1.f);
  launch_gemm<1,128,64,0,1,1>(stream, 49,8,1, bufO,1,0,0,512, fvWo,1,0,0,512,
      bufA2,1,0,0,512, fvb + 1536, bufX1, nullptr, 6272,512,512, 1.f);
  ln_k<<<1568, blk, 0, stream>>>(bufA2, fvln + 1024, fvln + 1536, bufLN, 6272);
  launch_gemm<0,128,64,1,0,1>(stream, 49,32,1, bufLN,1,0,0,512, fvW1t,1,0,0,512,
      bufS,1,0,0,2048, fvb1, nullptr, nullptr, 6272,2048,512, 1.f);
  launch_gemm<1,128,64,0,2,1>(stream, 49,8,1, bufS,1,0,0,2048, fvW2t,1,0,0,2048,
      bufA2,1,0,0,512, fvb2, bufA2, bufX1, 6272,512,2048, 1.f);
  ln_k<<<1568, blk, 0, stream>>>(bufA2, ldmln + 0, ldmln + 512, bufMED, 6272);

  // ================= Phase C: v_af = af(med, x, x) =================
  transpose_k<0><<<dim3(32,32), blk, 0, stream>>>(xbf, bufT, 256, 512, 256, 4, 1, 131072L, 0L, 131072L);
  launch_gemm<0,128,64,0,0,1>(stream, 49,8,1, bufMED,1,0,0,512, afW00,1,0,0,512,
      bufQ,1,0,0,512, afb + 0, nullptr, nullptr, 6272,512,512, 1.f);
  launch_gemm<0,64,64,0,0,0>(stream, 4,4,32, bufQ,1,100352L,0L,512, xbf,1,131072L,0L,512,
      bufS,1,50176L,0L,256, nullptr, nullptr, nullptr, 196,256,512, AFS);
  softmax_k<<<ceildiv(6272,4), blk, 0, stream>>>(bufS, 6272, 256);
  launch_gemm<0,64,64,0,0,0>(stream, 4,8,32, bufS,1,50176L,0L,256, bufT,1,131072L,0L,256,
      bufO,1,100352L,0L,512, nullptr, nullptr, nullptr, 196,512,256, 1.f);
  launch_gemm<0,128,64,0,0,1>(stream, 49,8,1, bufO,1,0,0,512, afW01,1,0,0,512,
      bufKV,1,0,0,512, afb + 512, nullptr, nullptr, 6272,512,512, 1.f);
  transpose_k<0><<<dim3(32,32), blk, 0, stream>>>(bufKV, bufT, 196, 512, 256, 4, 1, 100352L, 0L, 131072L);

  // ================= Phase D: out = af(x, med, v_af) + x =================
  launch_gemm<0,128,64,0,0,1>(stream, 64,8,1, xbf,1,0,0,512, afW10,1,0,0,512,
      bufQ,1,0,0,512, afb + 1024, nullptr, nullptr, 8192,512,512, 1.f);
  launch_gemm<0,64,64,0,0,0>(stream, 4,4,32, bufQ,1,131072L,0L,512, bufMED,1,100352L,0L,512,
      bufS,1,65536L,0L,256, nullptr, nullptr, nullptr, 256,196,512, AFS);
  softmax_k<<<ceildiv(8192,4), blk, 0, stream>>>(bufS, 8192, 196);
  launch_gemm<0,64,64,0,0,0>(stream, 4,8,32, bufS,1,65536L,0L,256, bufT,1,131072L,0L,256,
      bufO,1,131072L,0L,512, nullptr, nullptr, nullptr, 256,512,256, 1.f);
  launch_gemm<1,128,64,0,1,1>(stream, 64,8,1, bufO,1,0,0,512, afW11,1,0,0,512,
      out,1,0,0,512, afb + 1536, x, nullptr, 8192,512,512, 1.f);
}

// Round 5
// 429.346 us; speedup vs baseline: 1.7337x; 1.1693x over previous
//
#include <hip/hip_runtime.h>
#include <hip/hip_bf16.h>

typedef __attribute__((ext_vector_type(4))) float f32x4;
typedef __attribute__((ext_vector_type(8))) short s16x8;
typedef __attribute__((ext_vector_type(4))) short s16x4;

__device__ __forceinline__ short f2bf(float f) {
  union { float f; unsigned u; } c; c.f = f;
  unsigned r = c.u + 0x7fffu + ((c.u >> 16) & 1u);
  return (short)(r >> 16);
}
__device__ __forceinline__ float bf2f(short h) {
  union { unsigned u; float f; } c; c.u = ((unsigned)(unsigned short)h) << 16;
  return c.f;
}
__device__ __forceinline__ s16x8 cvt8(const f32x4& lo, const f32x4& hi) {
  s16x8 v;
  v[0] = f2bf(lo[0]); v[1] = f2bf(lo[1]); v[2] = f2bf(lo[2]); v[3] = f2bf(lo[3]);
  v[4] = f2bf(hi[0]); v[5] = f2bf(hi[1]); v[6] = f2bf(hi[2]); v[7] = f2bf(hi[3]);
  return v;
}

__device__ __forceinline__ void gl_lds16(const short* g, char* l) {
  __builtin_amdgcn_global_load_lds(
      (const __attribute__((address_space(1))) unsigned int*)g,
      (__attribute__((address_space(3))) unsigned int*)l, 16, 0, 0);
}

// ---------------------------------------------------------------------------
// Generalized MFMA GEMM (all-bf16 in): C = alpha*A[M,K]@B[N,K]^T (+bias/res)
//   WRN x WCN wave grid; RING-deep LDS ring with counted vmcnt;
//   SM=1: row-softmax epilogue (requires WCN=1, grid-n=1, BN>=N, nvalid mask)
// ---------------------------------------------------------------------------
template<int CF32, int BM, int BN, int WRN, int WCN, int RING,
         int SM, int RELU, int NRES, int SWZ>
__global__ __launch_bounds__(256, 2)
void gemm_k(const short* __restrict__ Ap, int hbA, long sAo, long sAi, int lda,
            const short* __restrict__ Bp, int hbB, long sBo, long sBi, int ldb,
            void* __restrict__ Cp, int hbC, long sCo, long sCi, int ldc,
            const float* __restrict__ bias,
            const float* __restrict__ res1,
            const float* __restrict__ res2,
            int M, int N, int K, float alpha, int nvalid)
{
  constexpr int MI = BM / (WRN * 16), NI = BN / (WCN * 16);
  constexpr int ACH = BM / 32, BCH = BN / 32;
  constexpr int L   = ACH + BCH;
  constexpr int ABYTES = BM * 128;
  constexpr int TBYTES = (BM + BN) * 128;
  __shared__ __align__(16) char smem[RING * TBYTES];

  const int tid  = threadIdx.x;
  const int lane = tid & 63;
  const int wid  = tid >> 6;
  const int wr   = wid / WCN, wc = wid % WCN;
  const int z    = blockIdx.z;

  int bx = blockIdx.x, by = blockIdx.y;
  if constexpr (SWZ) {
    const int gx = gridDim.x, gy = gridDim.y;
    const int nwg = gx * gy;
    const int o = by * gx + bx;
    const int q = nwg >> 3, r = nwg & 7;
    const int xcd = o & 7, slot = o >> 3;
    const int w = (xcd < r ? xcd * (q + 1) : r * (q + 1) + (xcd - r) * q) + slot;
    bx = w / gy; by = w - bx * gy;
  }
  const int m0 = bx * BM, n0 = by * BN;

  const int zA = z / hbA, zAi = z - zA * hbA;
  const int zB = z / hbB, zBi = z - zB * hbB;
  const int zC = z / hbC, zCi = z - zC * hbC;
  const short* Ab = Ap + (long)zA * sAo + (long)zAi * sAi;
  const short* Bb = Bp + (long)zB * sBo + (long)zBi * sBi;
  char*        Cb = (char*)Cp + ((long)zC * sCo + (long)zCi * sCi) * (CF32 ? 4 : 2);

  int aL[ACH]; long aG[ACH];
#pragma unroll
  for (int j = 0; j < ACH; ++j) {
    int chunk = (j * 4 + wid) * 64 + lane;
    int row = chunk >> 3;
    int c   = (chunk & 7) ^ (row & 7);
    int gr = m0 + row; if (gr > M - 1) gr = M - 1;
    aL[j] = chunk * 16;
    aG[j] = (long)gr * lda + c * 8;
  }
  int bL[BCH]; long bG[BCH];
#pragma unroll
  for (int j = 0; j < BCH; ++j) {
    int chunk = (j * 4 + wid) * 64 + lane;
    int row = chunk >> 3;
    int c   = (chunk & 7) ^ (row & 7);
    int gc = n0 + row; if (gc > N - 1) gc = N - 1;
    bL[j] = chunk * 16;
    bG[j] = (long)gc * ldb + c * 8;
  }

  auto stage = [&](int buf, int kt) {
    const short* Akt = Ab + (long)kt * 64;
    char* base = smem + buf * TBYTES;
#pragma unroll
    for (int j = 0; j < ACH; ++j) gl_lds16(Akt + aG[j], base + aL[j]);
    const short* Bkt = Bb + (long)kt * 64;
#pragma unroll
    for (int j = 0; j < BCH; ++j) gl_lds16(Bkt + bG[j], base + ABYTES + bL[j]);
  };

  int ard[2][MI], brd[2][NI];
#pragma unroll
  for (int kk = 0; kk < 2; ++kk) {
    int kgr = kk * 4 + (lane >> 4);
#pragma unroll
    for (int mi = 0; mi < MI; ++mi) {
      int m = wr * (BM / WRN) + mi * 16 + (lane & 15);
      ard[kk][mi] = m * 128 + ((kgr ^ (m & 7)) << 4);
    }
#pragma unroll
    for (int ni = 0; ni < NI; ++ni) {
      int n = wc * (BN / WCN) + ni * 16 + (lane & 15);
      brd[kk][ni] = ABYTES + n * 128 + ((kgr ^ (n & 7)) << 4);
    }
  }

  const int NT = K >> 6;
#pragma unroll
  for (int p = 0; p < RING; ++p) if (p < NT) stage(p, p);

  f32x4 acc[MI][NI];
#pragma unroll
  for (int mi = 0; mi < MI; ++mi)
#pragma unroll
    for (int ni = 0; ni < NI; ++ni) acc[mi][ni] = (f32x4){0.f, 0.f, 0.f, 0.f};

  int bufi = 0;
  for (int t = 0; t < NT; ++t) {
    const int rem = NT - t;
    if constexpr (RING == 3) {
      if (rem >= 3)      asm volatile("s_waitcnt vmcnt(%0)" :: "n"(2 * L) : "memory");
      else if (rem == 2) asm volatile("s_waitcnt vmcnt(%0)" :: "n"(L) : "memory");
      else               asm volatile("s_waitcnt vmcnt(0)" ::: "memory");
    } else if constexpr (RING == 2) {
      if (rem >= 2)      asm volatile("s_waitcnt vmcnt(%0)" :: "n"(L) : "memory");
      else               asm volatile("s_waitcnt vmcnt(0)" ::: "memory");
    } else {
      asm volatile("s_waitcnt vmcnt(0)" ::: "memory");
    }
    asm volatile("s_barrier" ::: "memory");

    const char* base = smem + bufi * TBYTES;
#pragma unroll
    for (int kk = 0; kk < 2; ++kk) {
      s16x8 af[MI];
#pragma unroll
      for (int mi = 0; mi < MI; ++mi) af[mi] = *(const s16x8*)(base + ard[kk][mi]);
#pragma unroll
      for (int ni = 0; ni < NI; ++ni) {
        s16x8 bf = *(const s16x8*)(base + brd[kk][ni]);
#pragma unroll
        for (int mi = 0; mi < MI; ++mi)
          acc[mi][ni] = __builtin_amdgcn_mfma_f32_16x16x32_bf16(af[mi], bf, acc[mi][ni], 0, 0, 0);
      }
    }

    if (t + RING < NT) {
      asm volatile("s_waitcnt lgkmcnt(0)" ::: "memory");
      asm volatile("s_barrier" ::: "memory");
      stage(bufi, t + RING);
    }
    bufi = (bufi + 1 == RING) ? 0 : bufi + 1;
  }

  // ---- optional softmax epilogue (wave-local rows; WCN must be 1) ----
  if constexpr (SM) {
#pragma unroll
    for (int mi = 0; mi < MI; ++mi) {
#pragma unroll
      for (int j = 0; j < 4; ++j) {
        float mx = -3.0e38f;
#pragma unroll
        for (int ni = 0; ni < NI; ++ni) {
          int col = n0 + wc * (BN / WCN) + ni * 16 + (lane & 15);
          float s = acc[mi][ni][j] * alpha;
          acc[mi][ni][j] = (col < nvalid) ? s : -3.0e38f;
          mx = fmaxf(mx, acc[mi][ni][j]);
        }
#pragma unroll
        for (int o = 1; o < 16; o <<= 1) mx = fmaxf(mx, __shfl_xor(mx, o));
        float sum = 0.f;
#pragma unroll
        for (int ni = 0; ni < NI; ++ni) {
          int col = n0 + wc * (BN / WCN) + ni * 16 + (lane & 15);
          float e = (col < nvalid) ? __expf(acc[mi][ni][j] - mx) : 0.f;
          acc[mi][ni][j] = e;
          sum += e;
        }
#pragma unroll
        for (int o = 1; o < 16; o <<= 1) sum += __shfl_xor(sum, o);
        float inv = 1.f / sum;
#pragma unroll
        for (int ni = 0; ni < NI; ++ni) acc[mi][ni][j] *= inv;
      }
    }
  }
  const float aep = SM ? 1.f : alpha;

  // ---- epilogue: acc -> LDS -> coalesced global ----
  asm volatile("s_waitcnt lgkmcnt(0)" ::: "memory");
  __syncthreads();

  constexpr int LSTR = BN + (CF32 ? 4 : 8);
  {
    float* lf = (float*)smem;
    short* lh = (short*)smem;
#pragma unroll
    for (int mi = 0; mi < MI; ++mi)
#pragma unroll
      for (int ni = 0; ni < NI; ++ni) {
        int c_loc = wc * (BN / WCN) + ni * 16 + (lane & 15);
        float bv = bias ? bias[n0 + c_loc] : 0.f;
        int rb = wr * (BM / WRN) + mi * 16 + ((lane >> 4) << 2);
#pragma unroll
        for (int j = 0; j < 4; ++j) {
          float v = acc[mi][ni][j] * aep + bv;
          if constexpr (CF32) lf[(rb + j) * LSTR + c_loc] = v;
          else                lh[(rb + j) * LSTR + c_loc] = f2bf(v);
        }
      }
  }
  __syncthreads();

  constexpr int CPR = BN / 8;
  constexpr int RP  = 256 / CPR;
  const int rr0 = tid / CPR;
  const int cc  = (tid % CPR) * 8;
  for (int r = rr0; r < BM; r += RP) {
    const int gr = m0 + r;
    if (gr >= M) break;
    f32x4 a, b;
    if constexpr (CF32) {
      a = *(const f32x4*)((const float*)smem + (long)r * LSTR + cc);
      b = *(const f32x4*)((const float*)smem + (long)r * LSTR + cc + 4);
    } else {
      s16x8 h = *(const s16x8*)((const short*)smem + (long)r * LSTR + cc);
#pragma unroll
      for (int j = 0; j < 4; ++j) { a[j] = bf2f(h[j]); b[j] = bf2f(h[j + 4]); }
    }
    const long gb = (long)gr * ldc + n0 + cc;
    if constexpr (NRES >= 1) {
      f32x4 r1 = *(const f32x4*)(res1 + gb), r2 = *(const f32x4*)(res1 + gb + 4);
#pragma unroll
      for (int j = 0; j < 4; ++j) { a[j] += r1[j]; b[j] += r2[j]; }
    }
    if constexpr (NRES >= 2) {
      f32x4 r1 = *(const f32x4*)(res2 + gb), r2 = *(const f32x4*)(res2 + gb + 4);
#pragma unroll
      for (int j = 0; j < 4; ++j) { a[j] += r1[j]; b[j] += r2[j]; }
    }
    if constexpr (RELU) {
#pragma unroll
      for (int j = 0; j < 4; ++j) { a[j] = fmaxf(a[j], 0.f); b[j] = fmaxf(b[j], 0.f); }
    }
    if constexpr (CF32) {
      *(f32x4*)((float*)Cb + gb) = a;
      *(f32x4*)((float*)Cb + gb + 4) = b;
    } else {
      *(s16x8*)((short*)Cb + gb) = cvt8(a, b);
    }
  }
}

// ---------------------------------------------------------------------------
// Batched transpose (bf16 in) -> bf16 [C x Rpad], zero-pad rows R_in..Rpad-1
// ---------------------------------------------------------------------------
__global__ __launch_bounds__(256)
void transpose_k(const short* __restrict__ inp, short* __restrict__ outp,
                 int R_in, int rs_in, int Rpad, int tiles_r,
                 int hb, long sO, long sI, long out_bs)
{
  __shared__ float tile[64][65];
  const int z = blockIdx.y;
  const int zo = z / hb, zi = z - zo * hb;
  const short* in = inp + (long)zo * sO + (long)zi * sI;
  short* out = outp + (long)z * out_bs;
  const int zt = blockIdx.x;
  const int tr = zt % tiles_r, tc = zt / tiles_r;
  const int r0 = tr * 64, c0 = tc * 64;
  const int c = threadIdx.x & 63, l0 = threadIdx.x >> 6;

#pragma unroll 4
  for (int i = 0; i < 16; ++i) {
    int l = l0 + i * 4;
    int gr = r0 + l;
    float v = 0.f;
    if (gr < R_in) v = bf2f(in[(long)gr * rs_in + c0 + c]);
    tile[l][c] = v;
  }
  __syncthreads();
#pragma unroll 4
  for (int i = 0; i < 16; ++i) {
    int cr = l0 + i * 4;
    out[(long)(c0 + cr) * Rpad + r0 + c] = f2bf(tile[c][cr]);
  }
}

// ---------------------------------------------------------------------------
// Batched weight transpose (fp32 in, up to 3 source groups) -> bf16 [N][K]
// ---------------------------------------------------------------------------
__global__ __launch_bounds__(256)
void transposeW_k(const float* s0, const float* s1, const float* s2,
                  short* d0, short* d1, short* d2,
                  int R_in, int rs_in, int Rpad, int tiles_r,
                  int per, long sI, long out_bs)
{
  __shared__ float tile[64][65];
  const int z = blockIdx.y;
  const int grp = z / per, idx = z - grp * per;
  const float* in = (grp == 0 ? s0 : grp == 1 ? s1 : s2) + (long)idx * sI;
  short* out = (grp == 0 ? d0 : grp == 1 ? d1 : d2) + (long)idx * out_bs;
  const int zt = blockIdx.x;
  const int tr = zt % tiles_r, tc = zt / tiles_r;
  const int r0 = tr * 64, c0 = tc * 64;
  const int c = threadIdx.x & 63, l0 = threadIdx.x >> 6;

#pragma unroll 4
  for (int i = 0; i < 16; ++i) {
    int l = l0 + i * 4;
    int gr = r0 + l;
    float v = 0.f;
    if (gr < R_in) v = in[(long)gr * rs_in + c0 + c];
    tile[l][c] = v;
  }
  __syncthreads();
#pragma unroll 4
  for (int i = 0; i < 16; ++i) {
    int cr = l0 + i * 4;
    out[(long)(c0 + cr) * Rpad + r0 + c] = f2bf(tile[c][cr]);
  }
}

// ---------------------------------------------------------------------------
// fused 3-array fp32 -> bf16 convert
// ---------------------------------------------------------------------------
__global__ __launch_bounds__(256)
void cvt3_k(const float* __restrict__ a, short* __restrict__ oa, long na,
            const float* __restrict__ b, short* __restrict__ ob, long nb,
            const float* __restrict__ c, short* __restrict__ oc, long nc)
{
  long i = ((long)blockIdx.x * 256 + threadIdx.x) * 8;
  const float* src; short* dst;
  if (i < na) { src = a + i; dst = oa + i; }
  else if (i < na + nb) { src = b + (i - na); dst = ob + (i - na); }
  else if (i < na + nb + nc) { src = c + (i - na - nb); dst = oc + (i - na - nb); }
  else return;
  f32x4 lo = *(const f32x4*)src, hi = *(const f32x4*)(src + 4);
  *(s16x8*)dst = cvt8(lo, hi);
}

// ---------------------------------------------------------------------------
// LayerNorm over D=512, one wave per row; bf16 out
// ---------------------------------------------------------------------------
__global__ __launch_bounds__(256)
void ln_k(const float* __restrict__ in, const float* __restrict__ g,
          const float* __restrict__ b, short* __restrict__ outp, int rows)
{
  int row = blockIdx.x * 4 + (threadIdx.x >> 6);
  if (row >= rows) return;
  int lane = threadIdx.x & 63;
  const float* p = in + (long)row * 512 + lane * 8;
  f32x4 v0 = *(const f32x4*)p, v1 = *(const f32x4*)(p + 4);
  float s = 0.f, sq = 0.f;
#pragma unroll
  for (int j = 0; j < 4; ++j) { s += v0[j] + v1[j]; sq += v0[j]*v0[j] + v1[j]*v1[j]; }
#pragma unroll
  for (int o = 1; o < 64; o <<= 1) { s += __shfl_xor(s, o); sq += __shfl_xor(sq, o); }
  float mean = s * (1.f / 512.f);
  float var  = sq * (1.f / 512.f) - mean * mean;
  float rs   = rsqrtf(var + 1e-6f);
  const f32x4 g0 = *(const f32x4*)(g + lane * 8), g1 = *(const f32x4*)(g + lane * 8 + 4);
  const f32x4 b0 = *(const f32x4*)(b + lane * 8), b1 = *(const f32x4*)(b + lane * 8 + 4);
  f32x4 o0, o1;
#pragma unroll
  for (int j = 0; j < 4; ++j) {
    o0[j] = g0[j] * (v0[j] - mean) * rs + b0[j];
    o1[j] = g1[j] * (v1[j] - mean) * rs + b1[j];
  }
  short* op = outp + (long)row * 512 + lane * 8;
  *(s16x8*)op = cvt8(o0, o1);
}

// ---------------------------------------------------------------------------
static inline int ceildiv(int a, int b) { return (a + b - 1) / b; }

template<int CF32, int BM, int BN, int WRN, int WCN, int RING,
         int SM, int RELU, int NRES, int SWZ>
static void launch_gemm(hipStream_t st, int gm, int gn, int gz,
                        const short* A, int hbA, long sAo, long sAi, int lda,
                        const short* B, int hbB, long sBo, long sBi, int ldb,
                        void* C, int hbC, long sCo, long sCi, int ldc,
                        const float* bias, const float* r1, const float* r2,
                        int M, int N, int K, float alpha, int nvalid)
{
  gemm_k<CF32, BM, BN, WRN, WCN, RING, SM, RELU, NRES, SWZ>
      <<<dim3(gm, gn, gz), dim3(256), 0, st>>>(
          A, hbA, sAo, sAi, lda, B, hbB, sBo, sBi, ldb,
          C, hbC, sCo, sCi, ldc, bias, r1, r2, M, N, K, alpha, nvalid);
}

extern "C" void kernel_launch(void* const* d_in, const int* in_sizes, int n_in,
                              void* d_out, int out_size, void* d_ws, size_t ws_size,
                              hipStream_t stream)
{
  (void)in_sizes; (void)n_in; (void)out_size; (void)ws_size;

  const float* x     = (const float*)d_in[0];   // [32,256,512]
  const float* text  = (const float*)d_in[1];   // [32,256,512]
  const float* vis   = (const float*)d_in[2];   // [32,196,512]
  const float* ftw   = (const float*)d_in[3];   // [4,512,512]
  const float* ftb   = (const float*)d_in[4];   // [4,512]
  const float* ftw1  = (const float*)d_in[5];   // [512,2048]
  const float* ftb1  = (const float*)d_in[6];
  const float* ftw2  = (const float*)d_in[7];   // [2048,512]
  const float* ftb2  = (const float*)d_in[8];
  const float* ftln  = (const float*)d_in[9];   // [2,2,512]
  const float* fvw   = (const float*)d_in[10];
  const float* fvb   = (const float*)d_in[11];
  const float* fvw1  = (const float*)d_in[12];
  const float* fvb1  = (const float*)d_in[13];
  const float* fvw2  = (const float*)d_in[14];
  const float* fvb2  = (const float*)d_in[15];
  const float* fvln  = (const float*)d_in[16];
  const float* ldmln = (const float*)d_in[17];  // [2,512]
  const float* afw   = (const float*)d_in[18];  // [2,2,512,512]
  const float* afb   = (const float*)d_in[19];  // [2,2,512]
  float* out = (float*)d_out;

  char* ws = (char*)d_ws;
  short* wT     = (short*)ws;                    // bf16 weights
  short* xbf    = (short*)(ws + 14680064);
  short* bufLN  = (short*)(ws + 23068672);
  short* bufQ   = (short*)(ws + 29491200);
  short* bufKV  = (short*)(ws + 37879808);       // [M][1024]
  short* bufT   = (short*)(ws + 54657024);
  short* bufS   = (short*)(ws + 63045632);       // scores / FFN hidden
  short* bufO   = (short*)(ws + 88735744);
  float* bufX1  = (float*)(ws + 97124352);
  float* bufA2  = (float*)(ws + 109969408);
  short* bufMED = (short*)(ws + 122814464);
  short* textbf = bufO;
  short* visbf  = (short*)bufA2;

  short* ftWq  = wT + 0;
  short* ftWk  = wT + 262144;   // Wk..Wv contiguous
  short* ftWo  = wT + 786432;
  short* ftW1t = wT + 1048576;
  short* ftW2t = wT + 2097152;
  short* fvWq  = wT + 3145728;
  short* fvWk  = wT + 3407872;
  short* fvWo  = wT + 3932160;
  short* fvW1t = wT + 4194304;
  short* fvW2t = wT + 5242880;
  short* afW00 = wT + 6291456;
  short* afW01 = wT + 6553600;
  short* afW10 = wT + 6815744;
  short* afW11 = wT + 7077888;

  const float AFS = 0.04419417382415922f; // 1/sqrt(512)
  dim3 blk(256);

  // ---- prep: 3 batched weight transposes + fused input convert ----
  transposeW_k<<<dim3(64, 12), blk, 0, stream>>>(ftw, fvw, afw, ftWq, fvWq, afW00,
      512, 512, 512, 8, 4, 262144L, 262144L);
  transposeW_k<<<dim3(256, 2), blk, 0, stream>>>(ftw1, fvw1, ftw1, ftW1t, fvW1t, ftW1t,
      512, 2048, 512, 8, 1, 0L, 0L);
  transposeW_k<<<dim3(256, 2), blk, 0, stream>>>(ftw2, fvw2, ftw2, ftW2t, fvW2t, ftW2t,
      2048, 512, 2048, 32, 1, 0L, 0L);
  cvt3_k<<<5664, blk, 0, stream>>>(x, xbf, 4194304L, text, textbf, 4194304L,
                                   vis, visbf, 3211264L);

  // ================= Phase A: cross_layer(vis, text, ft) =================
  ln_k<<<1568, blk, 0, stream>>>(vis, ftln + 0, ftln + 512, bufLN, 6272);
  launch_gemm<0,128,64,2,2,3,0,0,0,1>(stream, 49,8,1, bufLN,1,0,0,512, ftWq,1,0,0,512,
      bufQ,1,0,0,512, ftb + 0, nullptr, nullptr, 6272,512,512, 1.f, 0);
  launch_gemm<0,128,128,2,2,2,0,0,0,1>(stream, 64,8,1, textbf,1,0,0,512, ftWk,1,0,0,512,
      bufKV,1,0,0,1024, ftb + 512, nullptr, nullptr, 8192,1024,512, 1.f, 0);
  transpose_k<<<dim3(4,256), blk, 0, stream>>>(bufKV + 512, bufT, 256, 1024, 256, 4, 8, 262144L, 64L, 16384L);
  launch_gemm<0,64,256,4,1,1,1,0,0,0>(stream, 4,1,256, bufQ,8,100352L,64L,512, bufKV,8,262144L,64L,1024,
      bufS,1,50176L,0L,256, nullptr, nullptr, nullptr, 196,256,64, 0.125f, 256);
  launch_gemm<0,64,64,2,2,3,0,0,0,0>(stream, 4,1,256, bufS,1,50176L,0L,256, bufT,1,16384L,0L,256,
      bufO,8,100352L,64L,512, nullptr, nullptr, nullptr, 196,64,256, 1.f, 0);
  launch_gemm<1,128,64,2,2,3,0,0,1,1>(stream, 49,8,1, bufO,1,0,0,512, ftWo,1,0,0,512,
      bufX1,1,0,0,512, ftb + 1536, vis, nullptr, 6272,512,512, 1.f, 0);
  ln_k<<<1568, blk, 0, stream>>>(bufX1, ftln + 1024, ftln + 1536, bufLN, 6272);
  launch_gemm<0,128,128,2,2,2,0,1,0,1>(stream, 49,16,1, bufLN,1,0,0,512, ftW1t,1,0,0,512,
      bufS,1,0,0,2048, ftb1, nullptr, nullptr, 6272,2048,512, 1.f, 0);
  launch_gemm<1,128,64,2,2,3,0,0,1,1>(stream, 49,8,1, bufS,1,0,0,2048, ftW2t,1,0,0,2048,
      bufX1,1,0,0,512, ftb2, bufX1, nullptr, 6272,512,2048, 1.f, 0);

  // ================= Phase B: cross_layer(med1, vis, fv) + med1 =================
  ln_k<<<1568, blk, 0, stream>>>(bufX1, fvln + 0, fvln + 512, bufLN, 6272);
  launch_gemm<0,128,64,2,2,3,0,0,0,1>(stream, 49,8,1, bufLN,1,0,0,512, fvWq,1,0,0,512,
      bufQ,1,0,0,512, fvb + 0, nullptr, nullptr, 6272,512,512, 1.f, 0);
  launch_gemm<0,128,128,2,2,2,0,0,0,1>(stream, 49,8,1, visbf,1,0,0,512, fvWk,1,0,0,512,
      bufKV,1,0,0,1024, fvb + 512, nullptr, nullptr, 6272,1024,512, 1.f, 0);
  transpose_k<<<dim3(4,256), blk, 0, stream>>>(bufKV + 512, bufT, 196, 1024, 256, 4, 8, 200704L, 64L, 16384L);
  launch_gemm<0,64,256,4,1,1,1,0,0,0>(stream, 4,1,256, bufQ,8,100352L,64L,512, bufKV,8,200704L,64L,1024,
      bufS,1,50176L,0L,256, nullptr, nullptr, nullptr, 196,256,64, 0.125f, 196);
  launch_gemm<0,64,64,2,2,3,0,0,0,0>(stream, 4,1,256, bufS,1,50176L,0L,256, bufT,1,16384L,0L,256,
      bufO,8,100352L,64L,512, nullptr, nullptr, nullptr, 196,64,256, 1.f, 0);
  launch_gemm<1,128,64,2,2,3,0,0,1,1>(stream, 49,8,1, bufO,1,0,0,512, fvWo,1,0,0,512,
      bufA2,1,0,0,512, fvb + 1536, bufX1, nullptr, 6272,512,512, 1.f, 0);
  ln_k<<<1568, blk, 0, stream>>>(bufA2, fvln + 1024, fvln + 1536, bufLN, 6272);
  launch_gemm<0,128,128,2,2,2,0,1,0,1>(stream, 49,16,1, bufLN,1,0,0,512, fvW1t,1,0,0,512,
      bufS,1,0,0,2048, fvb1, nullptr, nullptr, 6272,2048,512, 1.f, 0);
  launch_gemm<1,128,64,2,2,3,0,0,2,1>(stream, 49,8,1, bufS,1,0,0,2048, fvW2t,1,0,0,2048,
      bufA2,1,0,0,512, fvb2, bufA2, bufX1, 6272,512,2048, 1.f, 0);
  ln_k<<<1568, blk, 0, stream>>>(bufA2, ldmln + 0, ldmln + 512, bufMED, 6272);

  // ================= Phase C: v_af = af(med, x, x) =================
  transpose_k<<<dim3(32,32), blk, 0, stream>>>(xbf, bufT, 256, 512, 256, 4, 1, 131072L, 0L, 131072L);
  launch_gemm<0,128,64,2,2,3,0,0,0,1>(stream, 49,8,1, bufMED,1,0,0,512, afW00,1,0,0,512,
      bufQ,1,0,0,512, afb + 0, nullptr, nullptr, 6272,512,512, 1.f, 0);
  launch_gemm<0,64,256,4,1,2,1,0,0,0>(stream, 4,1,32, bufQ,1,100352L,0L,512, xbf,1,131072L,0L,512,
      bufS,1,50176L,0L,256, nullptr, nullptr, nullptr, 196,256,512, AFS, 256);
  launch_gemm<0,64,64,2,2,3,0,0,0,0>(stream, 4,8,32, bufS,1,50176L,0L,256, bufT,1,131072L,0L,256,
      bufO,1,100352L,0L,512, nullptr, nullptr, nullptr, 196,512,256, 1.f, 0);
  launch_gemm<0,128,64,2,2,3,0,0,0,1>(stream, 49,8,1, bufO,1,0,0,512, afW01,1,0,0,512,
      bufKV,1,0,0,512, afb + 512, nullptr, nullptr, 6272,512,512, 1.f, 0);
  transpose_k<<<dim3(32,32), blk, 0, stream>>>(bufKV, bufT, 196, 512, 256, 4, 1, 100352L, 0L, 131072L);

  // ================= Phase D: out = af(x, med, v_af) + x =================
  launch_gemm<0,128,64,2,2,3,0,0,0,1>(stream, 64,8,1, xbf,1,0,0,512, afW10,1,0,0,512,
      bufQ,1,0,0,512, afb + 1024, nullptr, nullptr, 8192,512,512, 1.f, 0);
  launch_gemm<0,64,256,4,1,2,1,0,0,0>(stream, 4,1,32, bufQ,1,131072L,0L,512, bufMED,1,100352L,0L,512,
      bufS,1,65536L,0L,256, nullptr, nullptr, nullptr, 256,256,512, AFS, 196);
  launch_gemm<0,64,64,2,2,3,0,0,0,0>(stream, 4,8,32, bufS,1,65536L,0L,256, bufT,1,131072L,0L,256,
      bufO,1,131072L,0L,512, nullptr, nullptr, nullptr, 256,512,256, 1.f, 0);
  launch_gemm<1,128,64,2,2,3,0,0,1,1>(stream, 64,8,1, bufO,1,0,0,512, afW11,1,0,0,512,
      out,1,0,0,512, afb + 1536, x, nullptr, 8192,512,512, 1.f, 0);
}

// Round 6
// 406.399 us; speedup vs baseline: 1.8316x; 1.0565x over previous
//
#include <hip/hip_runtime.h>
#include <hip/hip_bf16.h>

typedef __attribute__((ext_vector_type(4))) float f32x4;
typedef __attribute__((ext_vector_type(8))) short s16x8;
typedef __attribute__((ext_vector_type(4))) short s16x4;

__device__ __forceinline__ short f2bf(float f) {
  union { float f; unsigned u; } c; c.f = f;
  unsigned r = c.u + 0x7fffu + ((c.u >> 16) & 1u);
  return (short)(r >> 16);
}
__device__ __forceinline__ float bf2f(short h) {
  union { unsigned u; float f; } c; c.u = ((unsigned)(unsigned short)h) << 16;
  return c.f;
}
__device__ __forceinline__ s16x8 cvt8(const f32x4& lo, const f32x4& hi) {
  s16x8 v;
  v[0] = f2bf(lo[0]); v[1] = f2bf(lo[1]); v[2] = f2bf(lo[2]); v[3] = f2bf(lo[3]);
  v[4] = f2bf(hi[0]); v[5] = f2bf(hi[1]); v[6] = f2bf(hi[2]); v[7] = f2bf(hi[3]);
  return v;
}

__device__ __forceinline__ void gl_lds16(const short* g, char* l) {
  __builtin_amdgcn_global_load_lds(
      (const __attribute__((address_space(1))) unsigned int*)g,
      (__attribute__((address_space(3))) unsigned int*)l, 16, 0, 0);
}

// ---------------------------------------------------------------------------
// Generalized MFMA GEMM (all-bf16 in): C = alpha*A[M,K]@B[N,K]^T (+bias/res)
// ---------------------------------------------------------------------------
template<int CF32, int BM, int BN, int WRN, int WCN, int RING,
         int SM, int RELU, int NRES, int SWZ>
__global__ __launch_bounds__(256, 2)
void gemm_k(const short* __restrict__ Ap, int hbA, long sAo, long sAi, int lda,
            const short* __restrict__ Bp, int hbB, long sBo, long sBi, int ldb,
            void* __restrict__ Cp, int hbC, long sCo, long sCi, int ldc,
            const float* __restrict__ bias,
            const float* __restrict__ res1,
            const float* __restrict__ res2,
            int M, int N, int K, float alpha, int nvalid)
{
  constexpr int MI = BM / (WRN * 16), NI = BN / (WCN * 16);
  constexpr int ACH = BM / 32, BCH = BN / 32;
  constexpr int L   = ACH + BCH;
  constexpr int ABYTES = BM * 128;
  constexpr int TBYTES = (BM + BN) * 128;
  __shared__ __align__(16) char smem[RING * TBYTES];

  const int tid  = threadIdx.x;
  const int lane = tid & 63;
  const int wid  = tid >> 6;
  const int wr   = wid / WCN, wc = wid % WCN;
  const int z    = blockIdx.z;

  int bx = blockIdx.x, by = blockIdx.y;
  if constexpr (SWZ) {
    const int gx = gridDim.x, gy = gridDim.y;
    const int nwg = gx * gy;
    const int o = by * gx + bx;
    const int q = nwg >> 3, r = nwg & 7;
    const int xcd = o & 7, slot = o >> 3;
    const int w = (xcd < r ? xcd * (q + 1) : r * (q + 1) + (xcd - r) * q) + slot;
    bx = w / gy; by = w - bx * gy;
  }
  const int m0 = bx * BM, n0 = by * BN;

  const int zA = z / hbA, zAi = z - zA * hbA;
  const int zB = z / hbB, zBi = z - zB * hbB;
  const int zC = z / hbC, zCi = z - zC * hbC;
  const short* Ab = Ap + (long)zA * sAo + (long)zAi * sAi;
  const short* Bb = Bp + (long)zB * sBo + (long)zBi * sBi;
  char*        Cb = (char*)Cp + ((long)zC * sCo + (long)zCi * sCi) * (CF32 ? 4 : 2);

  int aL[ACH]; long aG[ACH];
#pragma unroll
  for (int j = 0; j < ACH; ++j) {
    int chunk = (j * 4 + wid) * 64 + lane;
    int row = chunk >> 3;
    int c   = (chunk & 7) ^ (row & 7);
    int gr = m0 + row; if (gr > M - 1) gr = M - 1;
    aL[j] = chunk * 16;
    aG[j] = (long)gr * lda + c * 8;
  }
  int bL[BCH]; long bG[BCH];
#pragma unroll
  for (int j = 0; j < BCH; ++j) {
    int chunk = (j * 4 + wid) * 64 + lane;
    int row = chunk >> 3;
    int c   = (chunk & 7) ^ (row & 7);
    int gc = n0 + row; if (gc > N - 1) gc = N - 1;
    bL[j] = chunk * 16;
    bG[j] = (long)gc * ldb + c * 8;
  }

  auto stage = [&](int buf, int kt) {
    const short* Akt = Ab + (long)kt * 64;
    char* base = smem + buf * TBYTES;
#pragma unroll
    for (int j = 0; j < ACH; ++j) gl_lds16(Akt + aG[j], base + aL[j]);
    const short* Bkt = Bb + (long)kt * 64;
#pragma unroll
    for (int j = 0; j < BCH; ++j) gl_lds16(Bkt + bG[j], base + ABYTES + bL[j]);
  };

  int ard[2][MI], brd[2][NI];
#pragma unroll
  for (int kk = 0; kk < 2; ++kk) {
    int kgr = kk * 4 + (lane >> 4);
#pragma unroll
    for (int mi = 0; mi < MI; ++mi) {
      int m = wr * (BM / WRN) + mi * 16 + (lane & 15);
      ard[kk][mi] = m * 128 + ((kgr ^ (m & 7)) << 4);
    }
#pragma unroll
    for (int ni = 0; ni < NI; ++ni) {
      int n = wc * (BN / WCN) + ni * 16 + (lane & 15);
      brd[kk][ni] = ABYTES + n * 128 + ((kgr ^ (n & 7)) << 4);
    }
  }

  const int NT = K >> 6;
#pragma unroll
  for (int p = 0; p < RING; ++p) if (p < NT) stage(p, p);

  f32x4 acc[MI][NI];
#pragma unroll
  for (int mi = 0; mi < MI; ++mi)
#pragma unroll
    for (int ni = 0; ni < NI; ++ni) acc[mi][ni] = (f32x4){0.f, 0.f, 0.f, 0.f};

  int bufi = 0;
  for (int t = 0; t < NT; ++t) {
    const int rem = NT - t;
    if constexpr (RING == 3) {
      if (rem >= 3)      asm volatile("s_waitcnt vmcnt(%0)" :: "n"(2 * L) : "memory");
      else if (rem == 2) asm volatile("s_waitcnt vmcnt(%0)" :: "n"(L) : "memory");
      else               asm volatile("s_waitcnt vmcnt(0)" ::: "memory");
    } else if constexpr (RING == 2) {
      if (rem >= 2)      asm volatile("s_waitcnt vmcnt(%0)" :: "n"(L) : "memory");
      else               asm volatile("s_waitcnt vmcnt(0)" ::: "memory");
    } else {
      asm volatile("s_waitcnt vmcnt(0)" ::: "memory");
    }
    asm volatile("s_barrier" ::: "memory");

    const char* base = smem + bufi * TBYTES;
#pragma unroll
    for (int kk = 0; kk < 2; ++kk) {
      s16x8 af[MI];
#pragma unroll
      for (int mi = 0; mi < MI; ++mi) af[mi] = *(const s16x8*)(base + ard[kk][mi]);
#pragma unroll
      for (int ni = 0; ni < NI; ++ni) {
        s16x8 bf = *(const s16x8*)(base + brd[kk][ni]);
#pragma unroll
        for (int mi = 0; mi < MI; ++mi)
          acc[mi][ni] = __builtin_amdgcn_mfma_f32_16x16x32_bf16(af[mi], bf, acc[mi][ni], 0, 0, 0);
      }
    }

    if (t + RING < NT) {
      asm volatile("s_waitcnt lgkmcnt(0)" ::: "memory");
      asm volatile("s_barrier" ::: "memory");
      stage(bufi, t + RING);
    }
    bufi = (bufi + 1 == RING) ? 0 : bufi + 1;
  }

  if constexpr (SM) {
#pragma unroll
    for (int mi = 0; mi < MI; ++mi) {
#pragma unroll
      for (int j = 0; j < 4; ++j) {
        float mx = -3.0e38f;
#pragma unroll
        for (int ni = 0; ni < NI; ++ni) {
          int col = n0 + wc * (BN / WCN) + ni * 16 + (lane & 15);
          float s = acc[mi][ni][j] * alpha;
          acc[mi][ni][j] = (col < nvalid) ? s : -3.0e38f;
          mx = fmaxf(mx, acc[mi][ni][j]);
        }
#pragma unroll
        for (int o = 1; o < 16; o <<= 1) mx = fmaxf(mx, __shfl_xor(mx, o));
        float sum = 0.f;
#pragma unroll
        for (int ni = 0; ni < NI; ++ni) {
          int col = n0 + wc * (BN / WCN) + ni * 16 + (lane & 15);
          float e = (col < nvalid) ? __expf(acc[mi][ni][j] - mx) : 0.f;
          acc[mi][ni][j] = e;
          sum += e;
        }
#pragma unroll
        for (int o = 1; o < 16; o <<= 1) sum += __shfl_xor(sum, o);
        float inv = 1.f / sum;
#pragma unroll
        for (int ni = 0; ni < NI; ++ni) acc[mi][ni][j] *= inv;
      }
    }
  }
  const float aep = SM ? 1.f : alpha;

  asm volatile("s_waitcnt lgkmcnt(0)" ::: "memory");
  __syncthreads();

  constexpr int LSTR = BN + (CF32 ? 4 : 8);
  {
    float* lf = (float*)smem;
    short* lh = (short*)smem;
#pragma unroll
    for (int mi = 0; mi < MI; ++mi)
#pragma unroll
      for (int ni = 0; ni < NI; ++ni) {
        int c_loc = wc * (BN / WCN) + ni * 16 + (lane & 15);
        float bv = bias ? bias[n0 + c_loc] : 0.f;
        int rb = wr * (BM / WRN) + mi * 16 + ((lane >> 4) << 2);
#pragma unroll
        for (int j = 0; j < 4; ++j) {
          float v = acc[mi][ni][j] * aep + bv;
          if constexpr (CF32) lf[(rb + j) * LSTR + c_loc] = v;
          else                lh[(rb + j) * LSTR + c_loc] = f2bf(v);
        }
      }
  }
  __syncthreads();

  constexpr int CPR = BN / 8;
  constexpr int RP  = 256 / CPR;
  const int rr0 = tid / CPR;
  const int cc  = (tid % CPR) * 8;
  for (int r = rr0; r < BM; r += RP) {
    const int gr = m0 + r;
    if (gr >= M) break;
    f32x4 a, b;
    if constexpr (CF32) {
      a = *(const f32x4*)((const float*)smem + (long)r * LSTR + cc);
      b = *(const f32x4*)((const float*)smem + (long)r * LSTR + cc + 4);
    } else {
      s16x8 h = *(const s16x8*)((const short*)smem + (long)r * LSTR + cc);
#pragma unroll
      for (int j = 0; j < 4; ++j) { a[j] = bf2f(h[j]); b[j] = bf2f(h[j + 4]); }
    }
    const long gb = (long)gr * ldc + n0 + cc;
    if constexpr (NRES >= 1) {
      f32x4 r1 = *(const f32x4*)(res1 + gb), r2 = *(const f32x4*)(res1 + gb + 4);
#pragma unroll
      for (int j = 0; j < 4; ++j) { a[j] += r1[j]; b[j] += r2[j]; }
    }
    if constexpr (NRES >= 2) {
      f32x4 r1 = *(const f32x4*)(res2 + gb), r2 = *(const f32x4*)(res2 + gb + 4);
#pragma unroll
      for (int j = 0; j < 4; ++j) { a[j] += r1[j]; b[j] += r2[j]; }
    }
    if constexpr (RELU) {
#pragma unroll
      for (int j = 0; j < 4; ++j) { a[j] = fmaxf(a[j], 0.f); b[j] = fmaxf(b[j], 0.f); }
    }
    if constexpr (CF32) {
      *(f32x4*)((float*)Cb + gb) = a;
      *(f32x4*)((float*)Cb + gb + 4) = b;
    } else {
      *(s16x8*)((short*)Cb + gb) = cvt8(a, b);
    }
  }
}

// ---------------------------------------------------------------------------
// Fused MHA: per block (q-tile, b*8+h): S=Q@K^T -> softmax -> O=P@V
//   Q [Lq][512] head cols h*64; K [Lkv][ldk] head cols h*64;
//   V^T [64][256] per z (from bufT, keys zero-padded); O -> [Lq][512].
// LDS: Q 8K | K 32K (P overlays after barrier) | VT 32K = 72KB.
// ---------------------------------------------------------------------------
__global__ __launch_bounds__(256, 2)
void mha_k(const short* __restrict__ Qp, long qStride,
           const short* __restrict__ Kp, long kStride, int ldk, int Lkv,
           const short* __restrict__ VTp, long vtStride,
           short* __restrict__ Op, int Lq, float alpha, int nvalid)
{
  __shared__ __align__(16) char smem[73728];
  char* Qs  = smem;
  char* Ks  = smem + 8192;
  char* VTs = smem + 40960;

  const int tid = threadIdx.x, lane = tid & 63, wid = tid >> 6;
  const int z = blockIdx.z, b = z >> 3, h = z & 7;
  const int m0 = blockIdx.x * 64;

  const short* Qb  = Qp + (long)b * qStride + h * 64;
  const short* Kb  = Kp + (long)b * kStride + h * 64;
  const short* VTb = VTp + (long)z * vtStride;
  short*       Ob  = Op + (long)b * qStride + h * 64;

  // stage Q: [64][64], 512 chunks
#pragma unroll
  for (int j = 0; j < 2; ++j) {
    int chunk = (j * 4 + wid) * 64 + lane;
    int row = chunk >> 3, c = (chunk & 7) ^ (row & 7);
    int gr = m0 + row; if (gr > Lq - 1) gr = Lq - 1;
    gl_lds16(Qb + (long)gr * 512 + c * 8, Qs + chunk * 16);
  }
  // stage K: [256][64], 2048 chunks
#pragma unroll
  for (int j = 0; j < 8; ++j) {
    int chunk = (j * 4 + wid) * 64 + lane;
    int row = chunk >> 3, c = (chunk & 7) ^ (row & 7);
    int gr = row; if (gr > Lkv - 1) gr = Lkv - 1;
    gl_lds16(Kb + (long)gr * ldk + c * 8, Ks + chunk * 16);
  }
  // stage VT: [64][256], 2048 chunks, 32 chunks/row, swz low4 ^ row&15
#pragma unroll
  for (int j = 0; j < 8; ++j) {
    int chunk = (j * 4 + wid) * 64 + lane;
    int row = chunk >> 5, cw = (chunk & 31) ^ (row & 15);
    gl_lds16(VTb + (long)row * 256 + cw * 8, VTs + chunk * 16);
  }
  __syncthreads();

  // ---- QK^T: wave handles 16 q rows x 256 keys ----
  f32x4 acc[16];
#pragma unroll
  for (int ni = 0; ni < 16; ++ni) acc[ni] = (f32x4){0.f, 0.f, 0.f, 0.f};
#pragma unroll
  for (int kk = 0; kk < 2; ++kk) {
    int kgr = kk * 4 + (lane >> 4);
    int m = wid * 16 + (lane & 15);
    s16x8 af = *(const s16x8*)(Qs + m * 128 + ((kgr ^ (m & 7)) << 4));
#pragma unroll
    for (int ni = 0; ni < 16; ++ni) {
      int n = ni * 16 + (lane & 15);
      s16x8 bf = *(const s16x8*)(Ks + n * 128 + ((kgr ^ (n & 7)) << 4));
      acc[ni] = __builtin_amdgcn_mfma_f32_16x16x32_bf16(af, bf, acc[ni], 0, 0, 0);
    }
  }

  // ---- softmax over 256 keys (rows wave-local) ----
#pragma unroll
  for (int j = 0; j < 4; ++j) {
    float mx = -3.0e38f;
#pragma unroll
    for (int ni = 0; ni < 16; ++ni) {
      int col = ni * 16 + (lane & 15);
      float s = acc[ni][j] * alpha;
      acc[ni][j] = (col < nvalid) ? s : -3.0e38f;
      mx = fmaxf(mx, acc[ni][j]);
    }
#pragma unroll
    for (int o = 1; o < 16; o <<= 1) mx = fmaxf(mx, __shfl_xor(mx, o));
    float sum = 0.f;
#pragma unroll
    for (int ni = 0; ni < 16; ++ni) {
      int col = ni * 16 + (lane & 15);
      float e = (col < nvalid) ? __expf(acc[ni][j] - mx) : 0.f;
      acc[ni][j] = e;
      sum += e;
    }
#pragma unroll
    for (int o = 1; o < 16; o <<= 1) sum += __shfl_xor(sum, o);
    float inv = 1.f / sum;
#pragma unroll
    for (int ni = 0; ni < 16; ++ni) acc[ni][j] *= inv;
  }

  __syncthreads();   // all waves done reading Ks

  // ---- P -> LDS (wave-private, overlays Ks): [16 q][256 k], swz chunks ----
  {
    char* Ps = Ks + wid * 8192;
    const int r0 = (lane >> 4) * 4;
#pragma unroll
    for (int ni = 0; ni < 16; ++ni) {
      int col = ni * 16 + (lane & 15);
      int chunk = col >> 3, cin = (col & 7) * 2;
#pragma unroll
      for (int j = 0; j < 4; ++j) {
        int row = r0 + j;
        *(short*)(Ps + row * 512 + ((chunk ^ (row & 15)) << 4) + cin) = f2bf(acc[ni][j]);
      }
    }
  }
  asm volatile("s_waitcnt lgkmcnt(0)" ::: "memory");

  // ---- PV: O[16 q][64 d] per wave ----
  f32x4 acco[4];
#pragma unroll
  for (int ni = 0; ni < 4; ++ni) acco[ni] = (f32x4){0.f, 0.f, 0.f, 0.f};
  {
    const char* Ps = Ks + wid * 8192;
#pragma unroll
    for (int kk = 0; kk < 8; ++kk) {
      int g = lane >> 4;
      int mrow = lane & 15;
      int achunk = (kk * 4 + g) ^ (mrow & 15);
      s16x8 af = *(const s16x8*)(Ps + mrow * 512 + (achunk << 4));
#pragma unroll
      for (int ni = 0; ni < 4; ++ni) {
        int n = ni * 16 + (lane & 15);
        int bchunk = (kk * 4 + g) ^ (n & 15);
        s16x8 bf = *(const s16x8*)(VTs + n * 512 + (bchunk << 4));
        acco[ni] = __builtin_amdgcn_mfma_f32_16x16x32_bf16(af, bf, acco[ni], 0, 0, 0);
      }
    }
  }

  __syncthreads();

  // ---- O epilogue: LDS stage + coalesced store ----
  {
    short* lh = (short*)smem;
#pragma unroll
    for (int ni = 0; ni < 4; ++ni) {
      int d = ni * 16 + (lane & 15);
      int rb = wid * 16 + ((lane >> 4) << 2);
#pragma unroll
      for (int j = 0; j < 4; ++j) lh[(rb + j) * 72 + d] = f2bf(acco[ni][j]);
    }
  }
  __syncthreads();
  {
    const int r0 = tid >> 3, cc = (tid & 7) * 8;
#pragma unroll
    for (int p = 0; p < 2; ++p) {
      int r = r0 + p * 32;
      int gr = m0 + r;
      if (gr < Lq) {
        s16x8 h8 = *(const s16x8*)((const short*)smem + r * 72 + cc);
        *(s16x8*)(Ob + (long)gr * 512 + cc) = h8;
      }
    }
  }
}

// ---------------------------------------------------------------------------
// Batched transpose (bf16 in) -> bf16 [C x Rpad], zero-pad rows R_in..Rpad-1
// ---------------------------------------------------------------------------
__global__ __launch_bounds__(256)
void transpose_k(const short* __restrict__ inp, short* __restrict__ outp,
                 int R_in, int rs_in, int Rpad, int tiles_r,
                 int hb, long sO, long sI, long out_bs)
{
  __shared__ float tile[64][65];
  const int z = blockIdx.y;
  const int zo = z / hb, zi = z - zo * hb;
  const short* in = inp + (long)zo * sO + (long)zi * sI;
  short* out = outp + (long)z * out_bs;
  const int zt = blockIdx.x;
  const int tr = zt % tiles_r, tc = zt / tiles_r;
  const int r0 = tr * 64, c0 = tc * 64;
  const int c = threadIdx.x & 63, l0 = threadIdx.x >> 6;

#pragma unroll 4
  for (int i = 0; i < 16; ++i) {
    int l = l0 + i * 4;
    int gr = r0 + l;
    float v = 0.f;
    if (gr < R_in) v = bf2f(in[(long)gr * rs_in + c0 + c]);
    tile[l][c] = v;
  }
  __syncthreads();
#pragma unroll 4
  for (int i = 0; i < 16; ++i) {
    int cr = l0 + i * 4;
    out[(long)(c0 + cr) * Rpad + r0 + c] = f2bf(tile[c][cr]);
  }
}

// ---------------------------------------------------------------------------
// Batched weight transpose (fp32 in, up to 3 source groups) -> bf16 [N][K]
// ---------------------------------------------------------------------------
__global__ __launch_bounds__(256)
void transposeW_k(const float* s0, const float* s1, const float* s2,
                  short* d0, short* d1, short* d2,
                  int R_in, int rs_in, int Rpad, int tiles_r,
                  int per, long sI, long out_bs)
{
  __shared__ float tile[64][65];
  const int z = blockIdx.y;
  const int grp = z / per, idx = z - grp * per;
  const float* in = (grp == 0 ? s0 : grp == 1 ? s1 : s2) + (long)idx * sI;
  short* out = (grp == 0 ? d0 : grp == 1 ? d1 : d2) + (long)idx * out_bs;
  const int zt = blockIdx.x;
  const int tr = zt % tiles_r, tc = zt / tiles_r;
  const int r0 = tr * 64, c0 = tc * 64;
  const int c = threadIdx.x & 63, l0 = threadIdx.x >> 6;

#pragma unroll 4
  for (int i = 0; i < 16; ++i) {
    int l = l0 + i * 4;
    int gr = r0 + l;
    float v = 0.f;
    if (gr < R_in) v = in[(long)gr * rs_in + c0 + c];
    tile[l][c] = v;
  }
  __syncthreads();
#pragma unroll 4
  for (int i = 0; i < 16; ++i) {
    int cr = l0 + i * 4;
    out[(long)(c0 + cr) * Rpad + r0 + c] = f2bf(tile[c][cr]);
  }
}

// ---------------------------------------------------------------------------
__global__ __launch_bounds__(256)
void cvt3_k(const float* __restrict__ a, short* __restrict__ oa, long na,
            const float* __restrict__ b, short* __restrict__ ob, long nb,
            const float* __restrict__ c, short* __restrict__ oc, long nc)
{
  long i = ((long)blockIdx.x * 256 + threadIdx.x) * 8;
  const float* src; short* dst;
  if (i < na) { src = a + i; dst = oa + i; }
  else if (i < na + nb) { src = b + (i - na); dst = ob + (i - na); }
  else if (i < na + nb + nc) { src = c + (i - na - nb); dst = oc + (i - na - nb); }
  else return;
  f32x4 lo = *(const f32x4*)src, hi = *(const f32x4*)(src + 4);
  *(s16x8*)dst = cvt8(lo, hi);
}

// ---------------------------------------------------------------------------
__global__ __launch_bounds__(256)
void ln_k(const float* __restrict__ in, const float* __restrict__ g,
          const float* __restrict__ b, short* __restrict__ outp, int rows)
{
  int row = blockIdx.x * 4 + (threadIdx.x >> 6);
  if (row >= rows) return;
  int lane = threadIdx.x & 63;
  const float* p = in + (long)row * 512 + lane * 8;
  f32x4 v0 = *(const f32x4*)p, v1 = *(const f32x4*)(p + 4);
  float s = 0.f, sq = 0.f;
#pragma unroll
  for (int j = 0; j < 4; ++j) { s += v0[j] + v1[j]; sq += v0[j]*v0[j] + v1[j]*v1[j]; }
#pragma unroll
  for (int o = 1; o < 64; o <<= 1) { s += __shfl_xor(s, o); sq += __shfl_xor(sq, o); }
  float mean = s * (1.f / 512.f);
  float var  = sq * (1.f / 512.f) - mean * mean;
  float rs   = rsqrtf(var + 1e-6f);
  const f32x4 g0 = *(const f32x4*)(g + lane * 8), g1 = *(const f32x4*)(g + lane * 8 + 4);
  const f32x4 b0 = *(const f32x4*)(b + lane * 8), b1 = *(const f32x4*)(b + lane * 8 + 4);
  f32x4 o0, o1;
#pragma unroll
  for (int j = 0; j < 4; ++j) {
    o0[j] = g0[j] * (v0[j] - mean) * rs + b0[j];
    o1[j] = g1[j] * (v1[j] - mean) * rs + b1[j];
  }
  short* op = outp + (long)row * 512 + lane * 8;
  *(s16x8*)op = cvt8(o0, o1);
}

// ---------------------------------------------------------------------------
static inline int ceildiv(int a, int b) { return (a + b - 1) / b; }

template<int CF32, int BM, int BN, int WRN, int WCN, int RING,
         int SM, int RELU, int NRES, int SWZ>
static void launch_gemm(hipStream_t st, int gm, int gn, int gz,
                        const short* A, int hbA, long sAo, long sAi, int lda,
                        const short* B, int hbB, long sBo, long sBi, int ldb,
                        void* C, int hbC, long sCo, long sCi, int ldc,
                        const float* bias, const float* r1, const float* r2,
                        int M, int N, int K, float alpha, int nvalid)
{
  gemm_k<CF32, BM, BN, WRN, WCN, RING, SM, RELU, NRES, SWZ>
      <<<dim3(gm, gn, gz), dim3(256), 0, st>>>(
          A, hbA, sAo, sAi, lda, B, hbB, sBo, sBi, ldb,
          C, hbC, sCo, sCi, ldc, bias, r1, r2, M, N, K, alpha, nvalid);
}

extern "C" void kernel_launch(void* const* d_in, const int* in_sizes, int n_in,
                              void* d_out, int out_size, void* d_ws, size_t ws_size,
                              hipStream_t stream)
{
  (void)in_sizes; (void)n_in; (void)out_size; (void)ws_size;

  const float* x     = (const float*)d_in[0];
  const float* text  = (const float*)d_in[1];
  const float* vis   = (const float*)d_in[2];
  const float* ftw   = (const float*)d_in[3];
  const float* ftb   = (const float*)d_in[4];
  const float* ftw1  = (const float*)d_in[5];
  const float* ftb1  = (const float*)d_in[6];
  const float* ftw2  = (const float*)d_in[7];
  const float* ftb2  = (const float*)d_in[8];
  const float* ftln  = (const float*)d_in[9];
  const float* fvw   = (const float*)d_in[10];
  const float* fvb   = (const float*)d_in[11];
  const float* fvw1  = (const float*)d_in[12];
  const float* fvb1  = (const float*)d_in[13];
  const float* fvw2  = (const float*)d_in[14];
  const float* fvb2  = (const float*)d_in[15];
  const float* fvln  = (const float*)d_in[16];
  const float* ldmln = (const float*)d_in[17];
  const float* afw   = (const float*)d_in[18];
  const float* afb   = (const float*)d_in[19];
  float* out = (float*)d_out;

  char* ws = (char*)d_ws;
  short* wT     = (short*)ws;
  short* xbf    = (short*)(ws + 14680064);
  short* bufLN  = (short*)(ws + 23068672);
  short* bufQ   = (short*)(ws + 29491200);
  short* bufKV  = (short*)(ws + 37879808);
  short* bufT   = (short*)(ws + 54657024);
  short* bufS   = (short*)(ws + 63045632);
  short* bufO   = (short*)(ws + 88735744);
  float* bufX1  = (float*)(ws + 97124352);
  float* bufA2  = (float*)(ws + 109969408);
  short* bufMED = (short*)(ws + 122814464);
  short* textbf = bufO;
  short* visbf  = (short*)bufA2;

  short* ftWq  = wT + 0;
  short* ftWk  = wT + 262144;
  short* ftWo  = wT + 786432;
  short* ftW1t = wT + 1048576;
  short* ftW2t = wT + 2097152;
  short* fvWq  = wT + 3145728;
  short* fvWk  = wT + 3407872;
  short* fvWo  = wT + 3932160;
  short* fvW1t = wT + 4194304;
  short* fvW2t = wT + 5242880;
  short* afW00 = wT + 6291456;
  short* afW01 = wT + 6553600;
  short* afW10 = wT + 6815744;
  short* afW11 = wT + 7077888;

  const float AFS = 0.04419417382415922f;
  dim3 blk(256);

  // ---- prep ----
  transposeW_k<<<dim3(64, 12), blk, 0, stream>>>(ftw, fvw, afw, ftWq, fvWq, afW00,
      512, 512, 512, 8, 4, 262144L, 262144L);
  transposeW_k<<<dim3(256, 2), blk, 0, stream>>>(ftw1, fvw1, ftw1, ftW1t, fvW1t, ftW1t,
      512, 2048, 512, 8, 1, 0L, 0L);
  transposeW_k<<<dim3(256, 2), blk, 0, stream>>>(ftw2, fvw2, ftw2, ftW2t, fvW2t, ftW2t,
      2048, 512, 2048, 32, 1, 0L, 0L);
  cvt3_k<<<5664, blk, 0, stream>>>(x, xbf, 4194304L, text, textbf, 4194304L,
                                   vis, visbf, 3211264L);

  // ================= Phase A: cross_layer(vis, text, ft) =================
  ln_k<<<1568, blk, 0, stream>>>(vis, ftln + 0, ftln + 512, bufLN, 6272);
  launch_gemm<0,128,64,2,2,2,0,0,0,1>(stream, 49,8,1, bufLN,1,0,0,512, ftWq,1,0,0,512,
      bufQ,1,0,0,512, ftb + 0, nullptr, nullptr, 6272,512,512, 1.f, 0);
  launch_gemm<0,128,128,2,2,2,0,0,0,1>(stream, 64,8,1, textbf,1,0,0,512, ftWk,1,0,0,512,
      bufKV,1,0,0,1024, ftb + 512, nullptr, nullptr, 8192,1024,512, 1.f, 0);
  transpose_k<<<dim3(4,256), blk, 0, stream>>>(bufKV + 512, bufT, 256, 1024, 256, 4, 8, 262144L, 64L, 16384L);
  mha_k<<<dim3(4,1,256), blk, 0, stream>>>(bufQ, 100352L, bufKV, 262144L, 1024, 256,
      bufT, 16384L, bufO, 196, 0.125f, 256);
  launch_gemm<1,128,64,2,2,2,0,0,1,1>(stream, 49,8,1, bufO,1,0,0,512, ftWo,1,0,0,512,
      bufX1,1,0,0,512, ftb + 1536, vis, nullptr, 6272,512,512, 1.f, 0);
  ln_k<<<1568, blk, 0, stream>>>(bufX1, ftln + 1024, ftln + 1536, bufLN, 6272);
  launch_gemm<0,128,128,2,2,2,0,1,0,1>(stream, 49,16,1, bufLN,1,0,0,512, ftW1t,1,0,0,512,
      bufS,1,0,0,2048, ftb1, nullptr, nullptr, 6272,2048,512, 1.f, 0);
  launch_gemm<1,128,64,2,2,2,0,0,1,1>(stream, 49,8,1, bufS,1,0,0,2048, ftW2t,1,0,0,2048,
      bufX1,1,0,0,512, ftb2, bufX1, nullptr, 6272,512,2048, 1.f, 0);

  // ================= Phase B: cross_layer(med1, vis, fv) + med1 =================
  ln_k<<<1568, blk, 0, stream>>>(bufX1, fvln + 0, fvln + 512, bufLN, 6272);
  launch_gemm<0,128,64,2,2,2,0,0,0,1>(stream, 49,8,1, bufLN,1,0,0,512, fvWq,1,0,0,512,
      bufQ,1,0,0,512, fvb + 0, nullptr, nullptr, 6272,512,512, 1.f, 0);
  launch_gemm<0,128,128,2,2,2,0,0,0,1>(stream, 49,8,1, visbf,1,0,0,512, fvWk,1,0,0,512,
      bufKV,1,0,0,1024, fvb + 512, nullptr, nullptr, 6272,1024,512, 1.f, 0);
  transpose_k<<<dim3(4,256), blk, 0, stream>>>(bufKV + 512, bufT, 196, 1024, 256, 4, 8, 200704L, 64L, 16384L);
  mha_k<<<dim3(4,1,256), blk, 0, stream>>>(bufQ, 100352L, bufKV, 200704L, 1024, 196,
      bufT, 16384L, bufO, 196, 0.125f, 196);
  launch_gemm<1,128,64,2,2,2,0,0,1,1>(stream, 49,8,1, bufO,1,0,0,512, fvWo,1,0,0,512,
      bufA2,1,0,0,512, fvb + 1536, bufX1, nullptr, 6272,512,512, 1.f, 0);
  ln_k<<<1568, blk, 0, stream>>>(bufA2, fvln + 1024, fvln + 1536, bufLN, 6272);
  launch_gemm<0,128,128,2,2,2,0,1,0,1>(stream, 49,16,1, bufLN,1,0,0,512, fvW1t,1,0,0,512,
      bufS,1,0,0,2048, fvb1, nullptr, nullptr, 6272,2048,512, 1.f, 0);
  launch_gemm<1,128,64,2,2,2,0,0,2,1>(stream, 49,8,1, bufS,1,0,0,2048, fvW2t,1,0,0,2048,
      bufA2,1,0,0,512, fvb2, bufA2, bufX1, 6272,512,2048, 1.f, 0);
  ln_k<<<1568, blk, 0, stream>>>(bufA2, ldmln + 0, ldmln + 512, bufMED, 6272);

  // ================= Phase C: v_af = af(med, x, x) =================
  transpose_k<<<dim3(32,32), blk, 0, stream>>>(xbf, bufT, 256, 512, 256, 4, 1, 131072L, 0L, 131072L);
  launch_gemm<0,128,64,2,2,2,0,0,0,1>(stream, 49,8,1, bufMED,1,0,0,512, afW00,1,0,0,512,
      bufQ,1,0,0,512, afb + 0, nullptr, nullptr, 6272,512,512, 1.f, 0);
  launch_gemm<0,64,256,4,1,2,1,0,0,0>(stream, 4,1,32, bufQ,1,100352L,0L,512, xbf,1,131072L,0L,512,
      bufS,1,50176L,0L,256, nullptr, nullptr, nullptr, 196,256,512, AFS, 256);
  launch_gemm<0,64,64,2,2,3,0,0,0,0>(stream, 4,8,32, bufS,1,50176L,0L,256, bufT,1,131072L,0L,256,
      bufO,1,100352L,0L,512, nullptr, nullptr, nullptr, 196,512,256, 1.f, 0);
  launch_gemm<0,128,64,2,2,2,0,0,0,1>(stream, 49,8,1, bufO,1,0,0,512, afW01,1,0,0,512,
      bufKV,1,0,0,512, afb + 512, nullptr, nullptr, 6272,512,512, 1.f, 0);
  transpose_k<<<dim3(32,32), blk, 0, stream>>>(bufKV, bufT, 196, 512, 256, 4, 1, 100352L, 0L, 131072L);

  // ================= Phase D: out = af(x, med, v_af) + x =================
  launch_gemm<0,128,64,2,2,2,0,0,0,1>(stream, 64,8,1, xbf,1,0,0,512, afW10,1,0,0,512,
      bufQ,1,0,0,512, afb + 1024, nullptr, nullptr, 8192,512,512, 1.f, 0);
  launch_gemm<0,64,256,4,1,2,1,0,0,0>(stream, 4,1,32, bufQ,1,131072L,0L,512, bufMED,1,100352L,0L,512,
      bufS,1,65536L,0L,256, nullptr, nullptr, nullptr, 256,256,512, AFS, 196);
  launch_gemm<0,64,64,2,2,3,0,0,0,0>(stream, 4,8,32, bufS,1,65536L,0L,256, bufT,1,131072L,0L,256,
      bufO,1,131072L,0L,512, nullptr, nullptr, nullptr, 256,512,256, 1.f, 0);
  launch_gemm<1,128,64,2,2,2,0,0,1,1>(stream, 64,8,1, bufO,1,0,0,512, afW11,1,0,0,512,
      out,1,0,0,512, afb + 1536, x, nullptr, 8192,512,512, 1.f, 0);
}